// Round 4
// baseline (460.754 us; speedup 1.0000x reference)
//
#include <hip/hip_runtime.h>

typedef unsigned short u16;
typedef unsigned int   u32;

#define BB 4
#define CC 256
#define CI 128
#define NN 8192
#define N2 2048

// ws layout (bytes). R4: y buffer replaced by theta for b=2,3 (same size).
#define PHI_OFF   0u           // phi pooled fp16 [b][m][ci]: 4*2048*128*2 = 2,097,152
#define CAN0_OFF  2097152u
#define GP_OFF    2097168u     // g pooled fp16 [b][ci][m]: 2,097,152
#define CAN1_OFF  4194320u
#define THB_OFF   4194336u     // theta fp16 b=2,3: 2*8192*128*2 = 4,194,304
#define CAN2_OFF  8388640u
#define FLAG_OFF  8388644u
#define WHI_OFF   8388672u     // W_hi fp16 [3][128][256]: 196,608
#define WLO_OFF   8585280u     // W_lo fp16 [3][128][256]: 196,608
#define WFH_OFF   8781888u     // wf fp16 [256][128]: 65,536
#define WS_NEED   8847424u     // < 10,485,808 proven available

#define CAN0V 0xC0FFEE01u
#define CAN1V 0xC0FFEE02u
#define CAN2V 0xC0FFEE03u

#define LOG2E 1.4426950408889634f

typedef _Float16 f16;
typedef f16 f16x8 __attribute__((ext_vector_type(8)));
typedef float f32x4 __attribute__((ext_vector_type(4)));

__device__ __forceinline__ u16 f2h(float f) {
    _Float16 h = (_Float16)f;
    return __builtin_bit_cast(u16, h);
}
__device__ __forceinline__ float h2f(u16 u) {
    return (float)__builtin_bit_cast(_Float16, u);
}

// ---------------------------------------------------------------------------
__global__ __launch_bounds__(256) void fill_constf(float* out, float v, int n)
{
    int i = blockIdx.x * 256 + threadIdx.x;
    if (i < n) out[i] = v;
}

// Probe: x viewed as u32 fp32 words. R4: 4 INDEPENDENT named uint4 loads per
// thread (no register reuse -> no serialization), 2048 blocks = full occupancy.
__global__ __launch_bounds__(256) void probe_x(const u32* __restrict__ xv, u32* ws32)
{
    int gid = blockIdx.x * 256 + threadIdx.x;   // 524,288 threads
    const uint4* p = (const uint4*)xv;          // 2,097,152 uint4 total
    uint4 v0 = p[gid];
    uint4 v1 = p[gid + 524288];
    uint4 v2 = p[gid + 2 * 524288];
    uint4 v3 = p[gid + 3 * 524288];
    u32 ws_[16] = {v0.x, v0.y, v0.z, v0.w, v1.x, v1.y, v1.z, v1.w,
                   v2.x, v2.y, v2.z, v2.w, v3.x, v3.y, v3.z, v3.w};
    bool ff = false, nz = false;
#pragma unroll
    for (int j = 0; j < 16; j++) {
        u32 w = ws_[j];
        u32 lo = w & 0xffffu, hi = w >> 16;
        ff |= ((lo & 0x7f80u) == 0x7f80u) || ((hi & 0x7f80u) == 0x7f80u);
        nz |= (lo != 0u);
    }
    if (__any(ff) && (threadIdx.x & 63) == 0) atomicOr(&ws32[FLAG_OFF / 4], 1u);
    if (__any(nz) && (threadIdx.x & 63) == 0) atomicOr(&ws32[FLAG_OFF / 4], 2u);
}

// ---------------------------------------------------------------------------
// prep_w: split proj weights into fp16 hi+lo (compensated GEMM), wf -> fp16.
// ---------------------------------------------------------------------------
__global__ __launch_bounds__(256) void prep_w(
    const float* __restrict__ w0, const float* __restrict__ w1,
    const float* __restrict__ w2, const float* __restrict__ wf,
    u16* __restrict__ whi, u16* __restrict__ wlo, u16* __restrict__ wfh)
{
    int idx = blockIdx.x * 256 + threadIdx.x;
    if (idx < 98304) {
        int mb = idx >> 15, r = idx & 32767;
        float w = (mb == 0 ? w0 : (mb == 1 ? w1 : w2))[r];
        u16 hi = f2h(w);
        whi[idx] = hi;
        wlo[idx] = f2h(w - h2f(hi));
    } else {
        int r = idx - 98304;
        wfh[r] = f2h(wf[r]);
    }
}

// ---------------------------------------------------------------------------
// K1: projections via compensated fp16 MFMA: W_hi*x_hi + W_hi*x_lo + W_lo*x_hi
// (residual ~2^-22 rel => numerically fp32-exact). theta scaled by LOG2E
// (log2-domain scores). theta b=0,1 -> thA (d_out), b=2,3 -> thB (ws).
// ---------------------------------------------------------------------------
__global__ __launch_bounds__(256) void proj_mfma(
    const float* __restrict__ x,
    const float* __restrict__ b0v, const float* __restrict__ b1v,
    const float* __restrict__ b2v,
    const u16* __restrict__ whi, const u16* __restrict__ wlo,
    u16* __restrict__ thA, u16* __restrict__ thB,
    u16* __restrict__ phH, u16* __restrict__ gH,
    u32* __restrict__ ws32)
{
    // 48 KB: 2 x {xh 4KB | xl 4KB | wh 8KB | wl 8KB}; aliased as ot[64][132] f32 after loop
    __shared__ __align__(16) u16 smem[24576];
    int nb2 = blockIdx.x, mb = blockIdx.y, b = blockIdx.z;
    int tid = threadIdx.x;
    int lane = tid & 63, wid = tid >> 6, l15 = lane & 15, lg = lane >> 4;
    int n0 = nb2 * 64;

    const float* Bv = mb == 0 ? b0v : (mb == 1 ? b1v : b2v);
    const u16* whB = whi + mb * 32768;
    const u16* wlB = wlo + mb * 32768;

    int n_l = tid & 63, cg = tid >> 6;
    const float* xp = x + ((size_t)(b * CC + cg * 8)) * NN + n0 + n_l;
    int wci = tid >> 2, wkc = tid & 3;
    const u16* whp = whB + wci * 256 + wkc * 8;
    const u16* wlp = wlB + wci * 256 + wkc * 8;

    float xr[8];
    uint4 whr0, whr1, wlr0, wlr1;

#define PLOAD(s) do {                                                          \
    _Pragma("unroll") for (int j = 0; j < 8; j++)                              \
        xr[j] = xp[(size_t)((s) * 32 + j) * NN];                               \
    whr0 = *(const uint4*)(whp + (s) * 32);                                    \
    whr1 = *(const uint4*)(whp + 16384 + (s) * 32);                            \
    wlr0 = *(const uint4*)(wlp + (s) * 32);                                    \
    wlr1 = *(const uint4*)(wlp + 16384 + (s) * 32);                            \
} while (0)

#define PWRITE(bf) do {                                                        \
    u16* bp = smem + (bf) * 12288;                                             \
    u32 hw[4], lw[4];                                                          \
    _Pragma("unroll") for (int j = 0; j < 4; j++) {                            \
        u16 h0 = f2h(xr[2 * j]), h1 = f2h(xr[2 * j + 1]);                      \
        u16 q0 = f2h(xr[2 * j] - h2f(h0)), q1 = f2h(xr[2 * j + 1] - h2f(h1));  \
        hw[j] = (u32)h0 | ((u32)h1 << 16);                                     \
        lw[j] = (u32)q0 | ((u32)q1 << 16);                                     \
    }                                                                          \
    int xi = (n_l * 32 + cg * 8) ^ (((n_l >> 1) & 3) << 3);                    \
    *(uint4*)&bp[xi]        = make_uint4(hw[0], hw[1], hw[2], hw[3]);          \
    *(uint4*)&bp[2048 + xi] = make_uint4(lw[0], lw[1], lw[2], lw[3]);          \
    int wi = (wci * 32 + wkc * 8) ^ (((wci >> 1) & 3) << 3);                   \
    *(uint4*)&bp[4096 + wi]        = whr0;                                     \
    *(uint4*)&bp[4096 + wi + 2048] = whr1;                                     \
    *(uint4*)&bp[8192 + wi]        = wlr0;                                     \
    *(uint4*)&bp[8192 + wi + 2048] = wlr1;                                     \
} while (0)

    f32x4 acc[2][4];
#pragma unroll
    for (int i = 0; i < 2; i++)
#pragma unroll
        for (int j = 0; j < 4; j++) acc[i][j] = (f32x4){0.f, 0.f, 0.f, 0.f};

    PLOAD(0);
    PWRITE(0);
    PLOAD(1);
    __syncthreads();

    for (int t = 0; t < 8; t++) {
        int cur = t & 1;
        if (t + 1 < 8) PWRITE(cur ^ 1);
        if (t + 2 < 8) PLOAD(t + 2);
        const u16* bp = smem + cur * 12288;
        f16x8 ah[2], al[2], bh[4], bl[4];
#pragma unroll
        for (int rt = 0; rt < 2; rt++) {
            int r = wid * 32 + rt * 16 + l15;
            int idx = (r * 32 + lg * 8) ^ (((r >> 1) & 3) << 3);
            ah[rt] = *(const f16x8*)&bp[4096 + idx];
            al[rt] = *(const f16x8*)&bp[8192 + idx];
        }
#pragma unroll
        for (int ct = 0; ct < 4; ct++) {
            int n = ct * 16 + l15;
            int idx = (n * 32 + lg * 8) ^ (((n >> 1) & 3) << 3);
            bh[ct] = *(const f16x8*)&bp[idx];
            bl[ct] = *(const f16x8*)&bp[2048 + idx];
        }
#pragma unroll
        for (int rt = 0; rt < 2; rt++)
#pragma unroll
            for (int ct = 0; ct < 4; ct++) {
                acc[rt][ct] = __builtin_amdgcn_mfma_f32_16x16x32_f16(ah[rt], bh[ct], acc[rt][ct], 0, 0, 0);
                acc[rt][ct] = __builtin_amdgcn_mfma_f32_16x16x32_f16(ah[rt], bl[ct], acc[rt][ct], 0, 0, 0);
                acc[rt][ct] = __builtin_amdgcn_mfma_f32_16x16x32_f16(al[rt], bh[ct], acc[rt][ct], 0, 0, 0);
            }
        __syncthreads();
    }
#undef PLOAD
#undef PWRITE

    float* ot = (float*)smem;   // [64][132]
#pragma unroll
    for (int rt = 0; rt < 2; rt++) {
        int cb = wid * 32 + rt * 16 + lg * 4;
        float4 b4 = *(const float4*)&Bv[cb];
#pragma unroll
        for (int ct = 0; ct < 4; ct++) {
            int n = ct * 16 + l15;
            float4 v = make_float4(acc[rt][ct][0] + b4.x, acc[rt][ct][1] + b4.y,
                                   acc[rt][ct][2] + b4.z, acc[rt][ct][3] + b4.w);
            *(float4*)&ot[n * 132 + cb] = v;
        }
    }
    __syncthreads();

    int mb0 = (nb2 >> 4) * 256 + (nb2 & 15) * 16;

    if (mb == 0) {
        int nl = tid >> 2, sg = (tid & 3) * 32;
        u16* base = (b < 2) ? thA : thB;
        u16* dst = base + ((size_t)((b & 1) * NN + n0 + nl)) * CI + sg;
        const float* src = &ot[nl * 132 + sg];
#pragma unroll
        for (int i = 0; i < 4; i++) {
            u32 w[4];
#pragma unroll
            for (int j = 0; j < 4; j++)
                w[j] = (u32)f2h(src[i * 8 + 2 * j] * LOG2E) |
                       ((u32)f2h(src[i * 8 + 2 * j + 1] * LOG2E) << 16);
            ((uint4*)dst)[i] = make_uint4(w[0], w[1], w[2], w[3]);
        }
    } else if (mb == 1) {
        int ml = tid >> 4, cs = (tid & 15) * 8;
        int r0 = 2 * ml, r1 = r0 + 1, r2 = 32 + 2 * ml, r3 = r2 + 1;
        float pv[8];
#pragma unroll
        for (int j = 0; j < 8; j++)
            pv[j] = fmaxf(fmaxf(ot[r0 * 132 + cs + j], ot[r1 * 132 + cs + j]),
                          fmaxf(ot[r2 * 132 + cs + j], ot[r3 * 132 + cs + j]));
        u32 w[4];
#pragma unroll
        for (int j = 0; j < 4; j++)
            w[j] = (u32)f2h(pv[2 * j]) | ((u32)f2h(pv[2 * j + 1]) << 16);
        *(uint4*)(phH + ((size_t)(b * N2 + mb0 + ml)) * CI + cs) =
            make_uint4(w[0], w[1], w[2], w[3]);
    } else {
        int gci = tid >> 1, half = tid & 1;
        u32 res[4];
#pragma unroll
        for (int p = 0; p < 4; p++) {
            int m0 = half * 8 + 2 * p, m1 = m0 + 1;
            float v0 = fmaxf(fmaxf(ot[(2 * m0) * 132 + gci], ot[(2 * m0 + 1) * 132 + gci]),
                             fmaxf(ot[(32 + 2 * m0) * 132 + gci], ot[(33 + 2 * m0) * 132 + gci]));
            float v1 = fmaxf(fmaxf(ot[(2 * m1) * 132 + gci], ot[(2 * m1 + 1) * 132 + gci]),
                             fmaxf(ot[(32 + 2 * m1) * 132 + gci], ot[(33 + 2 * m1) * 132 + gci]));
            res[p] = (u32)f2h(v0) | ((u32)f2h(v1) << 16);
        }
        *(uint4*)(gH + ((size_t)(b * CI + gci)) * N2 + mb0 + half * 8) =
            make_uint4(res[0], res[1], res[2], res[3]);
    }
    if (nb2 == 0 && mb == 0 && b == 0 && tid == 0) {
        ws32[CAN0_OFF / 4] = CAN0V;
        ws32[CAN1_OFF / 4] = CAN1V;
        ws32[CAN2_OFF / 4] = CAN2V;
    }
}

// ---------------------------------------------------------------------------
// K2 (fused): MFMA flash attention + final conv + BN + residual.
// Attention loop identical to R3 (validated). Epilogue: y stays in LDS;
// per-wave GEMM out[c][n] = wf[c][:]·y[n][:] (A=wf from L2, B=y from LDS),
// then BN + residual -> out. Sentinel/canary logic moved here from final.
// ---------------------------------------------------------------------------
__global__ __launch_bounds__(256) void attn_fused(
    const u16* __restrict__ thH, const u16* __restrict__ phH,
    const u16* __restrict__ gH, const u16* __restrict__ wfh,
    const float* __restrict__ bfi, const float* __restrict__ gam,
    const float* __restrict__ bet, const float* __restrict__ mea,
    const float* __restrict__ varr, const float* __restrict__ x,
    const u32* __restrict__ ws32, float* __restrict__ out, int b0)
{
    __shared__ __align__(16) u16 th_s[64 * 128];
    __shared__ __align__(16) u16 kv_s[2][8192];
    __shared__ __align__(16) u16 p_s[4][512];
    __shared__ int flag;

    int tid = threadIdx.x;
    int lane = tid & 63, wid = tid >> 6;
    int l15 = lane & 15, lg = lane >> 4;
    int qb = blockIdx.x, b = b0 + blockIdx.y;

    if (tid == 0) {
        u32 pf = ws32[FLAG_OFF / 4];
        bool ws_ok = ws32[CAN0_OFF / 4] == CAN0V && ws32[CAN1_OFF / 4] == CAN1V &&
                     ws32[CAN2_OFF / 4] == CAN2V;
        bool is_bf16_input = ((pf & 1u) == 0u) && ((pf & 2u) != 0u);
        flag = is_bf16_input ? 2 : (ws_ok ? 0 : 1);
    }

    const u16* phB = phH + (size_t)b * N2 * CI;
    const u16* gB  = gH + (size_t)b * CI * N2;

    uint4 rph0, rph1, rv0, rv1;

#define LOADKV(k0) do {                                                                  \
    rph0 = *(const uint4*)(phB + ((size_t)((k0) + (tid >> 4))) * CI + (tid & 15) * 8);   \
    rph1 = *(const uint4*)(phB + ((size_t)((k0) + 16 + (tid >> 4))) * CI + (tid & 15) * 8); \
    rv0  = *(const uint4*)(gB + (size_t)(tid >> 2) * N2 + (k0) + (tid & 3) * 8);         \
    rv1  = *(const uint4*)(gB + (size_t)(64 + (tid >> 2)) * N2 + (k0) + (tid & 3) * 8);  \
} while (0)

#define WRITEKV(buf) do {                                                                \
    u16* ph_d = kv_s[buf]; u16* v_d = kv_s[buf] + 4096;                                  \
    { int key = tid >> 4;        int c8 = tid & 15;                                      \
      *(uint4*)&ph_d[(key * 128 + c8 * 8) ^ ((key & 7) << 3)] = rph0; }                  \
    { int key = 16 + (tid >> 4); int c8 = tid & 15;                                      \
      *(uint4*)&ph_d[(key * 128 + c8 * 8) ^ ((key & 7) << 3)] = rph1; }                  \
    { int d = tid >> 2;        int m8 = (tid & 3) * 8;                                   \
      *(uint4*)&v_d[(d * 32 + m8) ^ (((d >> 1) & 3) << 3)] = rv0; }                      \
    { int d = 64 + (tid >> 2); int m8 = (tid & 3) * 8;                                   \
      *(uint4*)&v_d[(d * 32 + m8) ^ (((d >> 1) & 3) << 3)] = rv1; }                      \
} while (0)

    {
        const uint4* ts = (const uint4*)(thH + ((size_t)((b - b0) * NN + qb * 64)) * CI);
#pragma unroll
        for (int i = 0; i < 4; i++) {
            int ch = i * 256 + tid;
            int q = ch >> 4, c8 = ch & 15;
            uint4 v = ts[ch];
            *(uint4*)&th_s[(q * 128 + c8 * 8) ^ ((q & 7) << 3)] = v;
        }
    }
    LOADKV(0);
    WRITEKV(0);
    LOADKV(32);
    __syncthreads();

    if (flag) {   // sentinel path (dtype model wrong / ws corrupt)
        float sig = flag == 2 ? 40000.f : 30000.f;
        size_t rowb = ((size_t)(b * CC + tid)) * NN + qb * 64;
        for (int n = 0; n < 64; n++) out[rowb + n] = sig;
        return;
    }

    f16x8 ath[4];
    {
        int qrow = wid * 16 + l15;
#pragma unroll
        for (int ks = 0; ks < 4; ks++)
            ath[ks] = *(const f16x8*)&th_s[(qrow * 128 + ks * 32 + lg * 8) ^ ((qrow & 7) << 3)];
    }

    f16x8 ones;
#pragma unroll
    for (int i = 0; i < 8; i++) ones[i] = (f16)1.0f;

    f32x4 Y[8];
#pragma unroll
    for (int i = 0; i < 8; i++) Y[i] = (f32x4){0.f, 0.f, 0.f, 0.f};
    f32x4 Yl = {0.f, 0.f, 0.f, 0.f};
    float m_run[4] = {-1e30f, -1e30f, -1e30f, -1e30f};

    for (int t = 0; t < 64; t++) {
        int cur = t & 1;
        if (t + 1 < 64) WRITEKV(cur ^ 1);
        if (t + 2 < 64) LOADKV((t + 2) * 32);

        const u16* ph_c = kv_s[cur];
        const u16* v_c  = kv_s[cur] + 4096;

        f32x4 S0 = {0.f, 0.f, 0.f, 0.f}, S1 = {0.f, 0.f, 0.f, 0.f};
#pragma unroll
        for (int ks = 0; ks < 4; ks++) {
            f16x8 bf0 = *(const f16x8*)&ph_c[(l15 * 128 + ks * 32 + lg * 8) ^ ((l15 & 7) << 3)];
            f16x8 bf1 = *(const f16x8*)&ph_c[((16 + l15) * 128 + ks * 32 + lg * 8) ^ (((16 + l15) & 7) << 3)];
            S0 = __builtin_amdgcn_mfma_f32_16x16x32_f16(ath[ks], bf0, S0, 0, 0, 0);
            S1 = __builtin_amdgcn_mfma_f32_16x16x32_f16(ath[ks], bf1, S1, 0, 0, 0);
        }

        // ---- online softmax, log2 domain ----
        float pmax[4], need = 0.f;
#pragma unroll
        for (int r = 0; r < 4; r++) {
            float v = fmaxf(S0[r], S1[r]);
            v = fmaxf(v, __shfl_xor(v, 1));
            v = fmaxf(v, __shfl_xor(v, 2));
            v = fmaxf(v, __shfl_xor(v, 4));
            v = fmaxf(v, __shfl_xor(v, 8));
            pmax[r] = v;
            need = fmaxf(need, v - m_run[r]);
        }
        if (__any(need > 11.5f)) {   // T13 defer-max
            float al[4];
#pragma unroll
            for (int r = 0; r < 4; r++) {
                float mn = fmaxf(m_run[r], pmax[r]);
                al[r] = __builtin_amdgcn_exp2f(m_run[r] - mn);
                m_run[r] = mn;
            }
#pragma unroll
            for (int i = 0; i < 8; i++) {
#pragma unroll
                for (int r = 0; r < 4; r++) Y[i][r] *= al[r];
            }
#pragma unroll
            for (int r = 0; r < 4; r++) Yl[r] *= al[r];
        }
        float p0[4], p1[4];
#pragma unroll
        for (int r = 0; r < 4; r++) {
            p0[r] = __builtin_amdgcn_exp2f(S0[r] - m_run[r]);
            p1[r] = __builtin_amdgcn_exp2f(S1[r] - m_run[r]);
        }

        {
            u16* pw = p_s[wid];
#pragma unroll
            for (int r = 0; r < 4; r++) {
                int q = lg * 4 + r;
                int sw = ((q >> 1) & 3) << 3;
                pw[(q * 32 + l15) ^ sw]      = f2h(p0[r]);
                pw[(q * 32 + 16 + l15) ^ sw] = f2h(p1[r]);
            }
        }
        __builtin_amdgcn_sched_barrier(0);

        f16x8 pa = *(const f16x8*)&p_s[wid][(l15 * 32 + lg * 8) ^ (((l15 >> 1) & 3) << 3)];
        Yl = __builtin_amdgcn_mfma_f32_16x16x32_f16(pa, ones, Yl, 0, 0, 0);
#pragma unroll
        for (int dt = 0; dt < 8; dt++) {
            int d = dt * 16 + l15;
            f16x8 bv = *(const f16x8*)&v_c[(d * 32 + lg * 8) ^ (((d >> 1) & 3) << 3)];
            Y[dt] = __builtin_amdgcn_mfma_f32_16x16x32_f16(pa, bv, Y[dt], 0, 0, 0);
        }
        __syncthreads();
    }

    // ---- y (normalized) -> LDS, swz ^((row&7)<<3) ----
    float inv[4];
#pragma unroll
    for (int r = 0; r < 4; r++) inv[r] = 1.f / Yl[r];
    u16* yl = (u16*)kv_s;   // 16 KB [64 n][128 ci]
#pragma unroll
    for (int dt = 0; dt < 8; dt++) {
#pragma unroll
        for (int r = 0; r < 4; r++) {
            int q = wid * 16 + lg * 4 + r;
            int d = dt * 16 + l15;
            yl[(q * 128 + d) ^ ((q & 7) << 3)] = f2h(Y[dt][r] * inv[r]);
        }
    }
    __syncthreads();

    // ---- fused final conv: out[c][n] = wf[c][:]·y[n][:], BN, +x ----
    f16x8 bfr[4][4];   // [ks][ct] y B-frags, hoisted (Y regs now free)
#pragma unroll
    for (int ks = 0; ks < 4; ks++)
#pragma unroll
        for (int ct = 0; ct < 4; ct++) {
            int n = ct * 16 + l15;
            bfr[ks][ct] = *(const f16x8*)&yl[(n * 128 + ks * 32 + lg * 8) ^ ((n & 7) << 3)];
        }

#pragma unroll
    for (int rt = 0; rt < 4; rt++) {
        int cb = wid * 64 + rt * 16;   // wave covers c in [wid*64, wid*64+64)
        f16x8 af[4];
#pragma unroll
        for (int ks = 0; ks < 4; ks++)
            af[ks] = *(const f16x8*)(wfh + (size_t)(cb + l15) * 128 + ks * 32 + lg * 8);
        f32x4 acc2[4];
#pragma unroll
        for (int ct = 0; ct < 4; ct++) acc2[ct] = (f32x4){0.f, 0.f, 0.f, 0.f};
#pragma unroll
        for (int ks = 0; ks < 4; ks++)
#pragma unroll
            for (int ct = 0; ct < 4; ct++)
                acc2[ct] = __builtin_amdgcn_mfma_f32_16x16x32_f16(af[ks], bfr[ks][ct], acc2[ct], 0, 0, 0);

        int c4 = cb + lg * 4;
        float4 g4 = *(const float4*)&gam[c4];
        float4 v4 = *(const float4*)&varr[c4];
        float4 m4 = *(const float4*)&mea[c4];
        float4 t4 = *(const float4*)&bet[c4];
        float4 f4 = *(const float4*)&bfi[c4];
        float iv[4], mn[4], bt[4], bv[4];
        iv[0] = g4.x / sqrtf(v4.x + 1e-5f); iv[1] = g4.y / sqrtf(v4.y + 1e-5f);
        iv[2] = g4.z / sqrtf(v4.z + 1e-5f); iv[3] = g4.w / sqrtf(v4.w + 1e-5f);
        mn[0] = m4.x; mn[1] = m4.y; mn[2] = m4.z; mn[3] = m4.w;
        bt[0] = t4.x; bt[1] = t4.y; bt[2] = t4.z; bt[3] = t4.w;
        bv[0] = f4.x; bv[1] = f4.y; bv[2] = f4.z; bv[3] = f4.w;
#pragma unroll
        for (int ct = 0; ct < 4; ct++) {
            int n = qb * 64 + ct * 16 + l15;
#pragma unroll
            for (int r = 0; r < 4; r++) {
                size_t o = ((size_t)(b * CC + c4 + r)) * NN + n;
                out[o] = (acc2[ct][r] + bv[r] - mn[r]) * iv[r] + bt[r] + x[o];
            }
        }
    }
#undef LOADKV
#undef WRITEKV
}

// ---------------------------------------------------------------------------
extern "C" void kernel_launch(void* const* d_in, const int* in_sizes, int n_in,
                              void* d_out, int out_size, void* d_ws, size_t ws_size,
                              hipStream_t stream)
{
    const int NOUT = BB * CC * NN;   // 8,388,608 elements
    bool sizes_ok = (n_in == 13) && (out_size == NOUT) &&
        in_sizes[0] == NOUT &&
        in_sizes[1] == CI * CC && in_sizes[2] == CI &&
        in_sizes[3] == CI * CC && in_sizes[4] == CI &&
        in_sizes[5] == CI * CC && in_sizes[6] == CI &&
        in_sizes[7] == CC * CI && in_sizes[8] == CC &&
        in_sizes[9] == CC && in_sizes[10] == CC && in_sizes[11] == CC && in_sizes[12] == CC;
    if (!sizes_ok || ws_size < (size_t)WS_NEED) {
        float sig = (!sizes_ok) ? 25000.f : 20000.f;
        hipLaunchKernelGGL(fill_constf, dim3((NOUT + 255) / 256), dim3(256), 0, stream,
                           (float*)d_out, sig, NOUT);
        return;
    }

    const float* x   = (const float*)d_in[0];
    const float* wth = (const float*)d_in[1];
    const float* bth = (const float*)d_in[2];
    const float* wph = (const float*)d_in[3];
    const float* bph = (const float*)d_in[4];
    const float* wg  = (const float*)d_in[5];
    const float* bg  = (const float*)d_in[6];
    const float* wf  = (const float*)d_in[7];
    const float* bfi = (const float*)d_in[8];
    const float* gam = (const float*)d_in[9];
    const float* bet = (const float*)d_in[10];
    const float* mea = (const float*)d_in[11];
    const float* var = (const float*)d_in[12];

    char* ws = (char*)d_ws;
    float* outF = (float*)d_out;                   // 33,554,432 B fp32
    u16*   thA  = (u16*)(outF + 4194304);          // theta b=0,1: d_out [16MB, 20MB)
    u16*   thB  = (u16*)(ws + THB_OFF);            // theta b=2,3: ws, 4 MB
    u16*   phHp = (u16*)(ws + PHI_OFF);
    u16*   gHp  = (u16*)(ws + GP_OFF);
    u16*   wHi  = (u16*)(ws + WHI_OFF);
    u16*   wLo  = (u16*)(ws + WLO_OFF);
    u16*   wFh  = (u16*)(ws + WFH_OFF);
    u32*   w32  = (u32*)ws;

    hipMemsetAsync(ws + FLAG_OFF, 0, 4, stream);
    hipLaunchKernelGGL(probe_x, dim3(2048), dim3(256), 0, stream, (const u32*)x, w32);
    hipLaunchKernelGGL(prep_w, dim3(512), dim3(256), 0, stream,
                       wth, wph, wg, wf, wHi, wLo, wFh);
    hipLaunchKernelGGL(proj_mfma, dim3(128, 3, 4), dim3(256), 0, stream,
                       x, bth, bph, bg, wHi, wLo, thA, thB, phHp, gHp, w32);
    // Launch 1 (b=0,1): writes out [0,16MB); theta thA at [16,20MB) untouched.
    hipLaunchKernelGGL(attn_fused, dim3(128, 2), dim3(256), 0, stream,
                       thA, phHp, gHp, wFh, bfi, gam, bet, mea, var, x, w32, outF, 0);
    // Launch 2 (b=2,3): writes out [16,32MB) (thA consumed); theta from ws.
    hipLaunchKernelGGL(attn_fused, dim3(128, 2), dim3(256), 0, stream,
                       thB, phHp, gHp, wFh, bfi, gam, bet, mea, var, x, w32, outF, 2);
}

// Round 5
// 278.913 us; speedup vs baseline: 1.6520x; 1.6520x over previous
//
#include <hip/hip_runtime.h>

typedef unsigned short u16;
typedef unsigned int   u32;

#define BB 4
#define CC 256
#define CI 128
#define NN 8192
#define N2 2048

// ws layout (bytes).
#define PHI_OFF   0u           // phi pooled fp16 [b][m][ci]: 4*2048*128*2 = 2,097,152
#define CAN0_OFF  2097152u
#define GP_OFF    2097168u     // g pooled fp16 [b][ci][m]: 2,097,152
#define CAN1_OFF  4194320u
#define THB_OFF   4194336u     // theta fp16 b=2,3: 2*8192*128*2 = 4,194,304
#define CAN2_OFF  8388640u
#define FLAG_OFF  8388644u
#define WHI_OFF   8388672u     // W_hi fp16 [3][128][256]: 196,608
#define WLO_OFF   8585280u     // W_lo fp16 [3][128][256]: 196,608
#define WFH_OFF   8781888u     // wf fp16 [256][128]: 65,536
#define PART_OFF  8847424u     // probe per-block partials: 2048*4 = 8,192
#define WS_NEED   8855616u     // < 10,485,808 proven available

#define CAN0V 0xC0FFEE01u
#define CAN1V 0xC0FFEE02u
#define CAN2V 0xC0FFEE03u

#define LOG2E 1.4426950408889634f

typedef _Float16 f16;
typedef f16 f16x8 __attribute__((ext_vector_type(8)));
typedef float f32x4 __attribute__((ext_vector_type(4)));

__device__ __forceinline__ u16 f2h(float f) {
    _Float16 h = (_Float16)f;
    return __builtin_bit_cast(u16, h);
}
__device__ __forceinline__ float h2f(u16 u) {
    return (float)__builtin_bit_cast(_Float16, u);
}

// ---------------------------------------------------------------------------
__global__ __launch_bounds__(256) void fill_constf(float* out, float v, int n)
{
    int i = blockIdx.x * 256 + threadIdx.x;
    if (i < n) out[i] = v;
}

// Probe: x viewed as u32 fp32 words. R5: NO ATOMICS (R4 post-mortem: 8192
// same-address atomicOrs @ ~23ns serialized = the whole 189us). Each block
// plain-stores one partial word; prep_w block 512 combines.
__global__ __launch_bounds__(256) void probe_x(const u32* __restrict__ xv,
                                               u32* __restrict__ part)
{
    __shared__ u32 red[4];
    int tid = threadIdx.x;
    int gid = blockIdx.x * 256 + tid;           // 524,288 threads
    const uint4* p = (const uint4*)xv;          // 2,097,152 uint4 total
    uint4 v0 = p[gid];
    uint4 v1 = p[gid + 524288];
    uint4 v2 = p[gid + 2 * 524288];
    uint4 v3 = p[gid + 3 * 524288];
    u32 ws_[16] = {v0.x, v0.y, v0.z, v0.w, v1.x, v1.y, v1.z, v1.w,
                   v2.x, v2.y, v2.z, v2.w, v3.x, v3.y, v3.z, v3.w};
    bool ff = false, nz = false;
#pragma unroll
    for (int j = 0; j < 16; j++) {
        u32 w = ws_[j];
        u32 lo = w & 0xffffu, hi = w >> 16;
        ff |= ((lo & 0x7f80u) == 0x7f80u) || ((hi & 0x7f80u) == 0x7f80u);
        nz |= (lo != 0u);
    }
    u32 wm = (__any(ff) ? 1u : 0u) | (__any(nz) ? 2u : 0u);
    if ((tid & 63) == 0) red[tid >> 6] = wm;
    __syncthreads();
    if (tid == 0) part[blockIdx.x] = red[0] | red[1] | red[2] | red[3];
}

// ---------------------------------------------------------------------------
// prep_w: blocks 0..511 split proj weights into fp16 hi+lo + wf -> fp16.
// Block 512: OR-combine probe partials -> flag word (runs after probe_x).
// ---------------------------------------------------------------------------
__global__ __launch_bounds__(256) void prep_w(
    const float* __restrict__ w0, const float* __restrict__ w1,
    const float* __restrict__ w2, const float* __restrict__ wf,
    u16* __restrict__ whi, u16* __restrict__ wlo, u16* __restrict__ wfh,
    const u32* __restrict__ part, u32* __restrict__ ws32)
{
    if (blockIdx.x < 512) {
        int idx = blockIdx.x * 256 + threadIdx.x;
        if (idx < 98304) {
            int mb = idx >> 15, r = idx & 32767;
            float w = (mb == 0 ? w0 : (mb == 1 ? w1 : w2))[r];
            u16 hi = f2h(w);
            whi[idx] = hi;
            wlo[idx] = f2h(w - h2f(hi));
        } else {
            int r = idx - 98304;
            wfh[r] = f2h(wf[r]);
        }
    } else {
        __shared__ u32 red[4];
        int tid = threadIdx.x;
        u32 m = 0;
#pragma unroll
        for (int i = 0; i < 8; i++) m |= part[tid * 8 + i];
        m |= __shfl_xor(m, 1);  m |= __shfl_xor(m, 2);  m |= __shfl_xor(m, 4);
        m |= __shfl_xor(m, 8);  m |= __shfl_xor(m, 16); m |= __shfl_xor(m, 32);
        if ((tid & 63) == 0) red[tid >> 6] = m;
        __syncthreads();
        if (tid == 0) ws32[FLAG_OFF / 4] = red[0] | red[1] | red[2] | red[3];
    }
}

// ---------------------------------------------------------------------------
// K1: projections via compensated fp16 MFMA: W_hi*x_hi + W_hi*x_lo + W_lo*x_hi
// (residual ~2^-22 rel => numerically fp32-exact). theta scaled by LOG2E
// (log2-domain scores). theta b=0,1 -> thA (d_out), b=2,3 -> thB (ws).
// ---------------------------------------------------------------------------
__global__ __launch_bounds__(256) void proj_mfma(
    const float* __restrict__ x,
    const float* __restrict__ b0v, const float* __restrict__ b1v,
    const float* __restrict__ b2v,
    const u16* __restrict__ whi, const u16* __restrict__ wlo,
    u16* __restrict__ thA, u16* __restrict__ thB,
    u16* __restrict__ phH, u16* __restrict__ gH,
    u32* __restrict__ ws32)
{
    // 48 KB: 2 x {xh 4KB | xl 4KB | wh 8KB | wl 8KB}; aliased as ot[64][132] f32 after loop
    __shared__ __align__(16) u16 smem[24576];
    int nb2 = blockIdx.x, mb = blockIdx.y, b = blockIdx.z;
    int tid = threadIdx.x;
    int lane = tid & 63, wid = tid >> 6, l15 = lane & 15, lg = lane >> 4;
    int n0 = nb2 * 64;

    const float* Bv = mb == 0 ? b0v : (mb == 1 ? b1v : b2v);
    const u16* whB = whi + mb * 32768;
    const u16* wlB = wlo + mb * 32768;

    int n_l = tid & 63, cg = tid >> 6;
    const float* xp = x + ((size_t)(b * CC + cg * 8)) * NN + n0 + n_l;
    int wci = tid >> 2, wkc = tid & 3;
    const u16* whp = whB + wci * 256 + wkc * 8;
    const u16* wlp = wlB + wci * 256 + wkc * 8;

    float xr[8];
    uint4 whr0, whr1, wlr0, wlr1;

#define PLOAD(s) do {                                                          \
    _Pragma("unroll") for (int j = 0; j < 8; j++)                              \
        xr[j] = xp[(size_t)((s) * 32 + j) * NN];                               \
    whr0 = *(const uint4*)(whp + (s) * 32);                                    \
    whr1 = *(const uint4*)(whp + 16384 + (s) * 32);                            \
    wlr0 = *(const uint4*)(wlp + (s) * 32);                                    \
    wlr1 = *(const uint4*)(wlp + 16384 + (s) * 32);                            \
} while (0)

#define PWRITE(bf) do {                                                        \
    u16* bp = smem + (bf) * 12288;                                             \
    u32 hw[4], lw[4];                                                          \
    _Pragma("unroll") for (int j = 0; j < 4; j++) {                            \
        u16 h0 = f2h(xr[2 * j]), h1 = f2h(xr[2 * j + 1]);                      \
        u16 q0 = f2h(xr[2 * j] - h2f(h0)), q1 = f2h(xr[2 * j + 1] - h2f(h1));  \
        hw[j] = (u32)h0 | ((u32)h1 << 16);                                     \
        lw[j] = (u32)q0 | ((u32)q1 << 16);                                     \
    }                                                                          \
    int xi = (n_l * 32 + cg * 8) ^ (((n_l >> 1) & 3) << 3);                    \
    *(uint4*)&bp[xi]        = make_uint4(hw[0], hw[1], hw[2], hw[3]);          \
    *(uint4*)&bp[2048 + xi] = make_uint4(lw[0], lw[1], lw[2], lw[3]);          \
    int wi = (wci * 32 + wkc * 8) ^ (((wci >> 1) & 3) << 3);                   \
    *(uint4*)&bp[4096 + wi]        = whr0;                                     \
    *(uint4*)&bp[4096 + wi + 2048] = whr1;                                     \
    *(uint4*)&bp[8192 + wi]        = wlr0;                                     \
    *(uint4*)&bp[8192 + wi + 2048] = wlr1;                                     \
} while (0)

    f32x4 acc[2][4];
#pragma unroll
    for (int i = 0; i < 2; i++)
#pragma unroll
        for (int j = 0; j < 4; j++) acc[i][j] = (f32x4){0.f, 0.f, 0.f, 0.f};

    PLOAD(0);
    PWRITE(0);
    PLOAD(1);
    __syncthreads();

    for (int t = 0; t < 8; t++) {
        int cur = t & 1;
        if (t + 1 < 8) PWRITE(cur ^ 1);
        if (t + 2 < 8) PLOAD(t + 2);
        const u16* bp = smem + cur * 12288;
        f16x8 ah[2], al[2], bh[4], bl[4];
#pragma unroll
        for (int rt = 0; rt < 2; rt++) {
            int r = wid * 32 + rt * 16 + l15;
            int idx = (r * 32 + lg * 8) ^ (((r >> 1) & 3) << 3);
            ah[rt] = *(const f16x8*)&bp[4096 + idx];
            al[rt] = *(const f16x8*)&bp[8192 + idx];
        }
#pragma unroll
        for (int ct = 0; ct < 4; ct++) {
            int n = ct * 16 + l15;
            int idx = (n * 32 + lg * 8) ^ (((n >> 1) & 3) << 3);
            bh[ct] = *(const f16x8*)&bp[idx];
            bl[ct] = *(const f16x8*)&bp[2048 + idx];
        }
#pragma unroll
        for (int rt = 0; rt < 2; rt++)
#pragma unroll
            for (int ct = 0; ct < 4; ct++) {
                acc[rt][ct] = __builtin_amdgcn_mfma_f32_16x16x32_f16(ah[rt], bh[ct], acc[rt][ct], 0, 0, 0);
                acc[rt][ct] = __builtin_amdgcn_mfma_f32_16x16x32_f16(ah[rt], bl[ct], acc[rt][ct], 0, 0, 0);
                acc[rt][ct] = __builtin_amdgcn_mfma_f32_16x16x32_f16(al[rt], bh[ct], acc[rt][ct], 0, 0, 0);
            }
        __syncthreads();
    }
#undef PLOAD
#undef PWRITE

    float* ot = (float*)smem;   // [64][132]
#pragma unroll
    for (int rt = 0; rt < 2; rt++) {
        int cb = wid * 32 + rt * 16 + lg * 4;
        float4 b4 = *(const float4*)&Bv[cb];
#pragma unroll
        for (int ct = 0; ct < 4; ct++) {
            int n = ct * 16 + l15;
            float4 v = make_float4(acc[rt][ct][0] + b4.x, acc[rt][ct][1] + b4.y,
                                   acc[rt][ct][2] + b4.z, acc[rt][ct][3] + b4.w);
            *(float4*)&ot[n * 132 + cb] = v;
        }
    }
    __syncthreads();

    int mb0 = (nb2 >> 4) * 256 + (nb2 & 15) * 16;

    if (mb == 0) {
        int nl = tid >> 2, sg = (tid & 3) * 32;
        u16* base = (b < 2) ? thA : thB;
        u16* dst = base + ((size_t)((b & 1) * NN + n0 + nl)) * CI + sg;
        const float* src = &ot[nl * 132 + sg];
#pragma unroll
        for (int i = 0; i < 4; i++) {
            u32 w[4];
#pragma unroll
            for (int j = 0; j < 4; j++)
                w[j] = (u32)f2h(src[i * 8 + 2 * j] * LOG2E) |
                       ((u32)f2h(src[i * 8 + 2 * j + 1] * LOG2E) << 16);
            ((uint4*)dst)[i] = make_uint4(w[0], w[1], w[2], w[3]);
        }
    } else if (mb == 1) {
        int ml = tid >> 4, cs = (tid & 15) * 8;
        int r0 = 2 * ml, r1 = r0 + 1, r2 = 32 + 2 * ml, r3 = r2 + 1;
        float pv[8];
#pragma unroll
        for (int j = 0; j < 8; j++)
            pv[j] = fmaxf(fmaxf(ot[r0 * 132 + cs + j], ot[r1 * 132 + cs + j]),
                          fmaxf(ot[r2 * 132 + cs + j], ot[r3 * 132 + cs + j]));
        u32 w[4];
#pragma unroll
        for (int j = 0; j < 4; j++)
            w[j] = (u32)f2h(pv[2 * j]) | ((u32)f2h(pv[2 * j + 1]) << 16);
        *(uint4*)(phH + ((size_t)(b * N2 + mb0 + ml)) * CI + cs) =
            make_uint4(w[0], w[1], w[2], w[3]);
    } else {
        int gci = tid >> 1, half = tid & 1;
        u32 res[4];
#pragma unroll
        for (int p = 0; p < 4; p++) {
            int m0 = half * 8 + 2 * p, m1 = m0 + 1;
            float v0 = fmaxf(fmaxf(ot[(2 * m0) * 132 + gci], ot[(2 * m0 + 1) * 132 + gci]),
                             fmaxf(ot[(32 + 2 * m0) * 132 + gci], ot[(33 + 2 * m0) * 132 + gci]));
            float v1 = fmaxf(fmaxf(ot[(2 * m1) * 132 + gci], ot[(2 * m1 + 1) * 132 + gci]),
                             fmaxf(ot[(32 + 2 * m1) * 132 + gci], ot[(33 + 2 * m1) * 132 + gci]));
            res[p] = (u32)f2h(v0) | ((u32)f2h(v1) << 16);
        }
        *(uint4*)(gH + ((size_t)(b * CI + gci)) * N2 + mb0 + half * 8) =
            make_uint4(res[0], res[1], res[2], res[3]);
    }
    if (nb2 == 0 && mb == 0 && b == 0 && tid == 0) {
        ws32[CAN0_OFF / 4] = CAN0V;
        ws32[CAN1_OFF / 4] = CAN1V;
        ws32[CAN2_OFF / 4] = CAN2V;
    }
}

// ---------------------------------------------------------------------------
// K2 (fused): MFMA flash attention + final conv + BN + residual.
// R5: theta A-frags load DIRECTLY global->reg (LDS stage was an identity
// round-trip); th_s removed (-16KB LDS, shorter prologue).
// ---------------------------------------------------------------------------
__global__ __launch_bounds__(256) void attn_fused(
    const u16* __restrict__ thH, const u16* __restrict__ phH,
    const u16* __restrict__ gH, const u16* __restrict__ wfh,
    const float* __restrict__ bfi, const float* __restrict__ gam,
    const float* __restrict__ bet, const float* __restrict__ mea,
    const float* __restrict__ varr, const float* __restrict__ x,
    const u32* __restrict__ ws32, float* __restrict__ out, int b0)
{
    __shared__ __align__(16) u16 kv_s[2][8192];
    __shared__ __align__(16) u16 p_s[4][512];
    __shared__ int flag;

    int tid = threadIdx.x;
    int lane = tid & 63, wid = tid >> 6;
    int l15 = lane & 15, lg = lane >> 4;
    int qb = blockIdx.x, b = b0 + blockIdx.y;

    if (tid == 0) {
        u32 pf = ws32[FLAG_OFF / 4];
        bool ws_ok = ws32[CAN0_OFF / 4] == CAN0V && ws32[CAN1_OFF / 4] == CAN1V &&
                     ws32[CAN2_OFF / 4] == CAN2V;
        bool is_bf16_input = ((pf & 1u) == 0u) && ((pf & 2u) != 0u);
        flag = is_bf16_input ? 2 : (ws_ok ? 0 : 1);
    }

    const u16* phB = phH + (size_t)b * N2 * CI;
    const u16* gB  = gH + (size_t)b * CI * N2;

    uint4 rph0, rph1, rv0, rv1;

#define LOADKV(k0) do {                                                                  \
    rph0 = *(const uint4*)(phB + ((size_t)((k0) + (tid >> 4))) * CI + (tid & 15) * 8);   \
    rph1 = *(const uint4*)(phB + ((size_t)((k0) + 16 + (tid >> 4))) * CI + (tid & 15) * 8); \
    rv0  = *(const uint4*)(gB + (size_t)(tid >> 2) * N2 + (k0) + (tid & 3) * 8);         \
    rv1  = *(const uint4*)(gB + (size_t)(64 + (tid >> 2)) * N2 + (k0) + (tid & 3) * 8);  \
} while (0)

#define WRITEKV(buf) do {                                                                \
    u16* ph_d = kv_s[buf]; u16* v_d = kv_s[buf] + 4096;                                  \
    { int key = tid >> 4;        int c8 = tid & 15;                                      \
      *(uint4*)&ph_d[(key * 128 + c8 * 8) ^ ((key & 7) << 3)] = rph0; }                  \
    { int key = 16 + (tid >> 4); int c8 = tid & 15;                                      \
      *(uint4*)&ph_d[(key * 128 + c8 * 8) ^ ((key & 7) << 3)] = rph1; }                  \
    { int d = tid >> 2;        int m8 = (tid & 3) * 8;                                   \
      *(uint4*)&v_d[(d * 32 + m8) ^ (((d >> 1) & 3) << 3)] = rv0; }                      \
    { int d = 64 + (tid >> 2); int m8 = (tid & 3) * 8;                                   \
      *(uint4*)&v_d[(d * 32 + m8) ^ (((d >> 1) & 3) << 3)] = rv1; }                      \
} while (0)

    // theta A-frags: direct global->reg (identical values to the old LDS path)
    f16x8 ath[4];
    {
        const u16* tp = thH + ((size_t)((b - b0) * NN + qb * 64 + wid * 16 + l15)) * CI;
#pragma unroll
        for (int ks = 0; ks < 4; ks++)
            ath[ks] = *(const f16x8*)(tp + ks * 32 + lg * 8);
    }
    LOADKV(0);
    WRITEKV(0);
    LOADKV(32);
    __syncthreads();

    if (flag) {   // sentinel path (dtype model wrong / ws corrupt)
        float sig = flag == 2 ? 40000.f : 30000.f;
        size_t rowb = ((size_t)(b * CC + tid)) * NN + qb * 64;
        for (int n = 0; n < 64; n++) out[rowb + n] = sig;
        return;
    }

    f16x8 ones;
#pragma unroll
    for (int i = 0; i < 8; i++) ones[i] = (f16)1.0f;

    f32x4 Y[8];
#pragma unroll
    for (int i = 0; i < 8; i++) Y[i] = (f32x4){0.f, 0.f, 0.f, 0.f};
    f32x4 Yl = {0.f, 0.f, 0.f, 0.f};
    float m_run[4] = {-1e30f, -1e30f, -1e30f, -1e30f};

    for (int t = 0; t < 64; t++) {
        int cur = t & 1;
        if (t + 1 < 64) WRITEKV(cur ^ 1);
        if (t + 2 < 64) LOADKV((t + 2) * 32);

        const u16* ph_c = kv_s[cur];
        const u16* v_c  = kv_s[cur] + 4096;

        f32x4 S0 = {0.f, 0.f, 0.f, 0.f}, S1 = {0.f, 0.f, 0.f, 0.f};
#pragma unroll
        for (int ks = 0; ks < 4; ks++) {
            f16x8 bf0 = *(const f16x8*)&ph_c[(l15 * 128 + ks * 32 + lg * 8) ^ ((l15 & 7) << 3)];
            f16x8 bf1 = *(const f16x8*)&ph_c[((16 + l15) * 128 + ks * 32 + lg * 8) ^ (((16 + l15) & 7) << 3)];
            S0 = __builtin_amdgcn_mfma_f32_16x16x32_f16(ath[ks], bf0, S0, 0, 0, 0);
            S1 = __builtin_amdgcn_mfma_f32_16x16x32_f16(ath[ks], bf1, S1, 0, 0, 0);
        }

        // ---- online softmax, log2 domain ----
        float pmax[4], need = 0.f;
#pragma unroll
        for (int r = 0; r < 4; r++) {
            float v = fmaxf(S0[r], S1[r]);
            v = fmaxf(v, __shfl_xor(v, 1));
            v = fmaxf(v, __shfl_xor(v, 2));
            v = fmaxf(v, __shfl_xor(v, 4));
            v = fmaxf(v, __shfl_xor(v, 8));
            pmax[r] = v;
            need = fmaxf(need, v - m_run[r]);
        }
        if (__any(need > 11.5f)) {   // T13 defer-max
            float al[4];
#pragma unroll
            for (int r = 0; r < 4; r++) {
                float mn = fmaxf(m_run[r], pmax[r]);
                al[r] = __builtin_amdgcn_exp2f(m_run[r] - mn);
                m_run[r] = mn;
            }
#pragma unroll
            for (int i = 0; i < 8; i++) {
#pragma unroll
                for (int r = 0; r < 4; r++) Y[i][r] *= al[r];
            }
#pragma unroll
            for (int r = 0; r < 4; r++) Yl[r] *= al[r];
        }
        float p0[4], p1[4];
#pragma unroll
        for (int r = 0; r < 4; r++) {
            p0[r] = __builtin_amdgcn_exp2f(S0[r] - m_run[r]);
            p1[r] = __builtin_amdgcn_exp2f(S1[r] - m_run[r]);
        }

        {
            u16* pw = p_s[wid];
#pragma unroll
            for (int r = 0; r < 4; r++) {
                int q = lg * 4 + r;
                int sw = ((q >> 1) & 3) << 3;
                pw[(q * 32 + l15) ^ sw]      = f2h(p0[r]);
                pw[(q * 32 + 16 + l15) ^ sw] = f2h(p1[r]);
            }
        }
        __builtin_amdgcn_sched_barrier(0);

        f16x8 pa = *(const f16x8*)&p_s[wid][(l15 * 32 + lg * 8) ^ (((l15 >> 1) & 3) << 3)];
        Yl = __builtin_amdgcn_mfma_f32_16x16x32_f16(pa, ones, Yl, 0, 0, 0);
#pragma unroll
        for (int dt = 0; dt < 8; dt++) {
            int d = dt * 16 + l15;
            f16x8 bv = *(const f16x8*)&v_c[(d * 32 + lg * 8) ^ (((d >> 1) & 3) << 3)];
            Y[dt] = __builtin_amdgcn_mfma_f32_16x16x32_f16(pa, bv, Y[dt], 0, 0, 0);
        }
        __syncthreads();
    }

    // ---- y (normalized) -> LDS, swz ^((row&7)<<3) ----
    float inv[4];
#pragma unroll
    for (int r = 0; r < 4; r++) inv[r] = 1.f / Yl[r];
    u16* yl = (u16*)kv_s;   // 16 KB [64 n][128 ci]
#pragma unroll
    for (int dt = 0; dt < 8; dt++) {
#pragma unroll
        for (int r = 0; r < 4; r++) {
            int q = wid * 16 + lg * 4 + r;
            int d = dt * 16 + l15;
            yl[(q * 128 + d) ^ ((q & 7) << 3)] = f2h(Y[dt][r] * inv[r]);
        }
    }
    __syncthreads();

    // ---- fused final conv: out[c][n] = wf[c][:]·y[n][:], BN, +x ----
    f16x8 bfr[4][4];   // [ks][ct] y B-frags, hoisted (Y regs now free)
#pragma unroll
    for (int ks = 0; ks < 4; ks++)
#pragma unroll
        for (int ct = 0; ct < 4; ct++) {
            int n = ct * 16 + l15;
            bfr[ks][ct] = *(const f16x8*)&yl[(n * 128 + ks * 32 + lg * 8) ^ ((n & 7) << 3)];
        }

#pragma unroll
    for (int rt = 0; rt < 4; rt++) {
        int cb = wid * 64 + rt * 16;   // wave covers c in [wid*64, wid*64+64)
        f16x8 af[4];
#pragma unroll
        for (int ks = 0; ks < 4; ks++)
            af[ks] = *(const f16x8*)(wfh + (size_t)(cb + l15) * 128 + ks * 32 + lg * 8);
        f32x4 acc2[4];
#pragma unroll
        for (int ct = 0; ct < 4; ct++) acc2[ct] = (f32x4){0.f, 0.f, 0.f, 0.f};
#pragma unroll
        for (int ks = 0; ks < 4; ks++)
#pragma unroll
            for (int ct = 0; ct < 4; ct++)
                acc2[ct] = __builtin_amdgcn_mfma_f32_16x16x32_f16(af[ks], bfr[ks][ct], acc2[ct], 0, 0, 0);

        int c4 = cb + lg * 4;
        float4 g4 = *(const float4*)&gam[c4];
        float4 v4 = *(const float4*)&varr[c4];
        float4 m4 = *(const float4*)&mea[c4];
        float4 t4 = *(const float4*)&bet[c4];
        float4 f4 = *(const float4*)&bfi[c4];
        float iv[4], mn[4], bt[4], bv[4];
        iv[0] = g4.x / sqrtf(v4.x + 1e-5f); iv[1] = g4.y / sqrtf(v4.y + 1e-5f);
        iv[2] = g4.z / sqrtf(v4.z + 1e-5f); iv[3] = g4.w / sqrtf(v4.w + 1e-5f);
        mn[0] = m4.x; mn[1] = m4.y; mn[2] = m4.z; mn[3] = m4.w;
        bt[0] = t4.x; bt[1] = t4.y; bt[2] = t4.z; bt[3] = t4.w;
        bv[0] = f4.x; bv[1] = f4.y; bv[2] = f4.z; bv[3] = f4.w;
#pragma unroll
        for (int ct = 0; ct < 4; ct++) {
            int n = qb * 64 + ct * 16 + l15;
#pragma unroll
            for (int r = 0; r < 4; r++) {
                size_t o = ((size_t)(b * CC + c4 + r)) * NN + n;
                out[o] = (acc2[ct][r] + bv[r] - mn[r]) * iv[r] + bt[r] + x[o];
            }
        }
    }
#undef LOADKV
#undef WRITEKV
}

// ---------------------------------------------------------------------------
extern "C" void kernel_launch(void* const* d_in, const int* in_sizes, int n_in,
                              void* d_out, int out_size, void* d_ws, size_t ws_size,
                              hipStream_t stream)
{
    const int NOUT = BB * CC * NN;   // 8,388,608 elements
    bool sizes_ok = (n_in == 13) && (out_size == NOUT) &&
        in_sizes[0] == NOUT &&
        in_sizes[1] == CI * CC && in_sizes[2] == CI &&
        in_sizes[3] == CI * CC && in_sizes[4] == CI &&
        in_sizes[5] == CI * CC && in_sizes[6] == CI &&
        in_sizes[7] == CC * CI && in_sizes[8] == CC &&
        in_sizes[9] == CC && in_sizes[10] == CC && in_sizes[11] == CC && in_sizes[12] == CC;
    if (!sizes_ok || ws_size < (size_t)WS_NEED) {
        float sig = (!sizes_ok) ? 25000.f : 20000.f;
        hipLaunchKernelGGL(fill_constf, dim3((NOUT + 255) / 256), dim3(256), 0, stream,
                           (float*)d_out, sig, NOUT);
        return;
    }

    const float* x   = (const float*)d_in[0];
    const float* wth = (const float*)d_in[1];
    const float* bth = (const float*)d_in[2];
    const float* wph = (const float*)d_in[3];
    const float* bph = (const float*)d_in[4];
    const float* wg  = (const float*)d_in[5];
    const float* bg  = (const float*)d_in[6];
    const float* wf  = (const float*)d_in[7];
    const float* bfi = (const float*)d_in[8];
    const float* gam = (const float*)d_in[9];
    const float* bet = (const float*)d_in[10];
    const float* mea = (const float*)d_in[11];
    const float* var = (const float*)d_in[12];

    char* ws = (char*)d_ws;
    float* outF = (float*)d_out;                   // 33,554,432 B fp32
    u16*   thA  = (u16*)(outF + 4194304);          // theta b=0,1: d_out [16MB, 20MB)
    u16*   thB  = (u16*)(ws + THB_OFF);            // theta b=2,3: ws, 4 MB
    u16*   phHp = (u16*)(ws + PHI_OFF);
    u16*   gHp  = (u16*)(ws + GP_OFF);
    u16*   wHi  = (u16*)(ws + WHI_OFF);
    u16*   wLo  = (u16*)(ws + WLO_OFF);
    u16*   wFh  = (u16*)(ws + WFH_OFF);
    u32*   part = (u32*)(ws + PART_OFF);
    u32*   w32  = (u32*)ws;

    hipLaunchKernelGGL(probe_x, dim3(2048), dim3(256), 0, stream, (const u32*)x, part);
    hipLaunchKernelGGL(prep_w, dim3(513), dim3(256), 0, stream,
                       wth, wph, wg, wf, wHi, wLo, wFh, part, w32);
    hipLaunchKernelGGL(proj_mfma, dim3(128, 3, 4), dim3(256), 0, stream,
                       x, bth, bph, bg, wHi, wLo, thA, thB, phHp, gHp, w32);
    // Launch 1 (b=0,1): writes out [0,16MB); theta thA at [16,20MB) untouched.
    hipLaunchKernelGGL(attn_fused, dim3(128, 2), dim3(256), 0, stream,
                       thA, phHp, gHp, wFh, bfi, gam, bet, mea, var, x, w32, outF, 0);
    // Launch 2 (b=2,3): writes out [16,32MB) (thA consumed); theta from ws.
    hipLaunchKernelGGL(attn_fused, dim3(128, 2), dim3(256), 0, stream,
                       thB, phHp, gHp, wFh, bfi, gam, bet, mea, var, x, w32, outF, 2);
}

// Round 6
// 227.573 us; speedup vs baseline: 2.0246x; 1.2256x over previous
//
#include <hip/hip_runtime.h>

typedef unsigned short u16;
typedef unsigned int   u32;

#define BB 4
#define CC 256
#define CI 128
#define NN 8192
#define N2 2048

// ws layout (bytes).
#define PHI_OFF   0u           // phi pooled fp16 [b][m][ci]: 4*2048*128*2 = 2,097,152
#define CAN0_OFF  2097152u
#define GP_OFF    2097168u     // g pooled fp16 [b][ci][m]: 2,097,152
#define CAN1_OFF  4194320u
#define THB_OFF   4194336u     // theta fp16 b=2,3: 2*8192*128*2 = 4,194,304
#define CAN2_OFF  8388640u
#define FLAG_OFF  8388644u
#define WHI_OFF   8388672u     // W_hi fp16 [3][128][256]: 196,608
#define WLO_OFF   8585280u     // W_lo fp16 [3][128][256]: 196,608
#define WFH_OFF   8781888u     // wf fp16 [256][128]: 65,536
#define PART_OFF  8847424u     // probe per-block partials: 2048*4 = 8,192
#define WS_NEED   8855616u     // < 10,485,808 proven available

#define CAN0V 0xC0FFEE01u
#define CAN1V 0xC0FFEE02u
#define CAN2V 0xC0FFEE03u

#define LOG2E 1.4426950408889634f

typedef _Float16 f16;
typedef f16 f16x8 __attribute__((ext_vector_type(8)));
typedef float f32x4 __attribute__((ext_vector_type(4)));

__device__ __forceinline__ u16 f2h(float f) {
    _Float16 h = (_Float16)f;
    return __builtin_bit_cast(u16, h);
}
__device__ __forceinline__ float h2f(u16 u) {
    return (float)__builtin_bit_cast(_Float16, u);
}

// ---------------------------------------------------------------------------
__global__ __launch_bounds__(256) void fill_constf(float* out, float v, int n)
{
    int i = blockIdx.x * 256 + threadIdx.x;
    if (i < n) out[i] = v;
}

// Probe: x viewed as u32 fp32 words. No atomics (R4 lesson): per-block
// plain-store partials; prep_w block 512 combines.
__global__ __launch_bounds__(256) void probe_x(const u32* __restrict__ xv,
                                               u32* __restrict__ part)
{
    __shared__ u32 red[4];
    int tid = threadIdx.x;
    int gid = blockIdx.x * 256 + tid;           // 524,288 threads
    const uint4* p = (const uint4*)xv;          // 2,097,152 uint4 total
    uint4 v0 = p[gid];
    uint4 v1 = p[gid + 524288];
    uint4 v2 = p[gid + 2 * 524288];
    uint4 v3 = p[gid + 3 * 524288];
    u32 ws_[16] = {v0.x, v0.y, v0.z, v0.w, v1.x, v1.y, v1.z, v1.w,
                   v2.x, v2.y, v2.z, v2.w, v3.x, v3.y, v3.z, v3.w};
    bool ff = false, nz = false;
#pragma unroll
    for (int j = 0; j < 16; j++) {
        u32 w = ws_[j];
        u32 lo = w & 0xffffu, hi = w >> 16;
        ff |= ((lo & 0x7f80u) == 0x7f80u) || ((hi & 0x7f80u) == 0x7f80u);
        nz |= (lo != 0u);
    }
    u32 wm = (__any(ff) ? 1u : 0u) | (__any(nz) ? 2u : 0u);
    if ((tid & 63) == 0) red[tid >> 6] = wm;
    __syncthreads();
    if (tid == 0) part[blockIdx.x] = red[0] | red[1] | red[2] | red[3];
}

// ---------------------------------------------------------------------------
// prep_w: blocks 0..511 split proj weights into fp16 hi+lo + wf -> fp16.
// Block 512: OR-combine probe partials -> flag word (runs after probe_x).
// ---------------------------------------------------------------------------
__global__ __launch_bounds__(256) void prep_w(
    const float* __restrict__ w0, const float* __restrict__ w1,
    const float* __restrict__ w2, const float* __restrict__ wf,
    u16* __restrict__ whi, u16* __restrict__ wlo, u16* __restrict__ wfh,
    const u32* __restrict__ part, u32* __restrict__ ws32)
{
    if (blockIdx.x < 512) {
        int idx = blockIdx.x * 256 + threadIdx.x;
        if (idx < 98304) {
            int mb = idx >> 15, r = idx & 32767;
            float w = (mb == 0 ? w0 : (mb == 1 ? w1 : w2))[r];
            u16 hi = f2h(w);
            whi[idx] = hi;
            wlo[idx] = f2h(w - h2f(hi));
        } else {
            int r = idx - 98304;
            wfh[r] = f2h(wf[r]);
        }
    } else {
        __shared__ u32 red[4];
        int tid = threadIdx.x;
        u32 m = 0;
#pragma unroll
        for (int i = 0; i < 8; i++) m |= part[tid * 8 + i];
        m |= __shfl_xor(m, 1);  m |= __shfl_xor(m, 2);  m |= __shfl_xor(m, 4);
        m |= __shfl_xor(m, 8);  m |= __shfl_xor(m, 16); m |= __shfl_xor(m, 32);
        if ((tid & 63) == 0) red[tid >> 6] = m;
        __syncthreads();
        if (tid == 0) ws32[FLAG_OFF / 4] = red[0] | red[1] | red[2] | red[3];
    }
}

// ---------------------------------------------------------------------------
// K1: projections via compensated fp16 MFMA (unchanged from R5 — validated).
// ---------------------------------------------------------------------------
__global__ __launch_bounds__(256) void proj_mfma(
    const float* __restrict__ x,
    const float* __restrict__ b0v, const float* __restrict__ b1v,
    const float* __restrict__ b2v,
    const u16* __restrict__ whi, const u16* __restrict__ wlo,
    u16* __restrict__ thA, u16* __restrict__ thB,
    u16* __restrict__ phH, u16* __restrict__ gH,
    u32* __restrict__ ws32)
{
    __shared__ __align__(16) u16 smem[24576];
    int nb2 = blockIdx.x, mb = blockIdx.y, b = blockIdx.z;
    int tid = threadIdx.x;
    int lane = tid & 63, wid = tid >> 6, l15 = lane & 15, lg = lane >> 4;
    int n0 = nb2 * 64;

    const float* Bv = mb == 0 ? b0v : (mb == 1 ? b1v : b2v);
    const u16* whB = whi + mb * 32768;
    const u16* wlB = wlo + mb * 32768;

    int n_l = tid & 63, cg = tid >> 6;
    const float* xp = x + ((size_t)(b * CC + cg * 8)) * NN + n0 + n_l;
    int wci = tid >> 2, wkc = tid & 3;
    const u16* whp = whB + wci * 256 + wkc * 8;
    const u16* wlp = wlB + wci * 256 + wkc * 8;

    float xr[8];
    uint4 whr0, whr1, wlr0, wlr1;

#define PLOAD(s) do {                                                          \
    _Pragma("unroll") for (int j = 0; j < 8; j++)                              \
        xr[j] = xp[(size_t)((s) * 32 + j) * NN];                               \
    whr0 = *(const uint4*)(whp + (s) * 32);                                    \
    whr1 = *(const uint4*)(whp + 16384 + (s) * 32);                            \
    wlr0 = *(const uint4*)(wlp + (s) * 32);                                    \
    wlr1 = *(const uint4*)(wlp + 16384 + (s) * 32);                            \
} while (0)

#define PWRITE(bf) do {                                                        \
    u16* bp = smem + (bf) * 12288;                                             \
    u32 hw[4], lw[4];                                                          \
    _Pragma("unroll") for (int j = 0; j < 4; j++) {                            \
        u16 h0 = f2h(xr[2 * j]), h1 = f2h(xr[2 * j + 1]);                      \
        u16 q0 = f2h(xr[2 * j] - h2f(h0)), q1 = f2h(xr[2 * j + 1] - h2f(h1));  \
        hw[j] = (u32)h0 | ((u32)h1 << 16);                                     \
        lw[j] = (u32)q0 | ((u32)q1 << 16);                                     \
    }                                                                          \
    int xi = (n_l * 32 + cg * 8) ^ (((n_l >> 1) & 3) << 3);                    \
    *(uint4*)&bp[xi]        = make_uint4(hw[0], hw[1], hw[2], hw[3]);          \
    *(uint4*)&bp[2048 + xi] = make_uint4(lw[0], lw[1], lw[2], lw[3]);          \
    int wi = (wci * 32 + wkc * 8) ^ (((wci >> 1) & 3) << 3);                   \
    *(uint4*)&bp[4096 + wi]        = whr0;                                     \
    *(uint4*)&bp[4096 + wi + 2048] = whr1;                                     \
    *(uint4*)&bp[8192 + wi]        = wlr0;                                     \
    *(uint4*)&bp[8192 + wi + 2048] = wlr1;                                     \
} while (0)

    f32x4 acc[2][4];
#pragma unroll
    for (int i = 0; i < 2; i++)
#pragma unroll
        for (int j = 0; j < 4; j++) acc[i][j] = (f32x4){0.f, 0.f, 0.f, 0.f};

    PLOAD(0);
    PWRITE(0);
    PLOAD(1);
    __syncthreads();

    for (int t = 0; t < 8; t++) {
        int cur = t & 1;
        if (t + 1 < 8) PWRITE(cur ^ 1);
        if (t + 2 < 8) PLOAD(t + 2);
        const u16* bp = smem + cur * 12288;
        f16x8 ah[2], al[2], bh[4], bl[4];
#pragma unroll
        for (int rt = 0; rt < 2; rt++) {
            int r = wid * 32 + rt * 16 + l15;
            int idx = (r * 32 + lg * 8) ^ (((r >> 1) & 3) << 3);
            ah[rt] = *(const f16x8*)&bp[4096 + idx];
            al[rt] = *(const f16x8*)&bp[8192 + idx];
        }
#pragma unroll
        for (int ct = 0; ct < 4; ct++) {
            int n = ct * 16 + l15;
            int idx = (n * 32 + lg * 8) ^ (((n >> 1) & 3) << 3);
            bh[ct] = *(const f16x8*)&bp[idx];
            bl[ct] = *(const f16x8*)&bp[2048 + idx];
        }
#pragma unroll
        for (int rt = 0; rt < 2; rt++)
#pragma unroll
            for (int ct = 0; ct < 4; ct++) {
                acc[rt][ct] = __builtin_amdgcn_mfma_f32_16x16x32_f16(ah[rt], bh[ct], acc[rt][ct], 0, 0, 0);
                acc[rt][ct] = __builtin_amdgcn_mfma_f32_16x16x32_f16(ah[rt], bl[ct], acc[rt][ct], 0, 0, 0);
                acc[rt][ct] = __builtin_amdgcn_mfma_f32_16x16x32_f16(al[rt], bh[ct], acc[rt][ct], 0, 0, 0);
            }
        __syncthreads();
    }
#undef PLOAD
#undef PWRITE

    float* ot = (float*)smem;   // [64][132]
#pragma unroll
    for (int rt = 0; rt < 2; rt++) {
        int cb = wid * 32 + rt * 16 + lg * 4;
        float4 b4 = *(const float4*)&Bv[cb];
#pragma unroll
        for (int ct = 0; ct < 4; ct++) {
            int n = ct * 16 + l15;
            float4 v = make_float4(acc[rt][ct][0] + b4.x, acc[rt][ct][1] + b4.y,
                                   acc[rt][ct][2] + b4.z, acc[rt][ct][3] + b4.w);
            *(float4*)&ot[n * 132 + cb] = v;
        }
    }
    __syncthreads();

    int mb0 = (nb2 >> 4) * 256 + (nb2 & 15) * 16;

    if (mb == 0) {
        int nl = tid >> 2, sg = (tid & 3) * 32;
        u16* base = (b < 2) ? thA : thB;
        u16* dst = base + ((size_t)((b & 1) * NN + n0 + nl)) * CI + sg;
        const float* src = &ot[nl * 132 + sg];
#pragma unroll
        for (int i = 0; i < 4; i++) {
            u32 w[4];
#pragma unroll
            for (int j = 0; j < 4; j++)
                w[j] = (u32)f2h(src[i * 8 + 2 * j] * LOG2E) |
                       ((u32)f2h(src[i * 8 + 2 * j + 1] * LOG2E) << 16);
            ((uint4*)dst)[i] = make_uint4(w[0], w[1], w[2], w[3]);
        }
    } else if (mb == 1) {
        int ml = tid >> 4, cs = (tid & 15) * 8;
        int r0 = 2 * ml, r1 = r0 + 1, r2 = 32 + 2 * ml, r3 = r2 + 1;
        float pv[8];
#pragma unroll
        for (int j = 0; j < 8; j++)
            pv[j] = fmaxf(fmaxf(ot[r0 * 132 + cs + j], ot[r1 * 132 + cs + j]),
                          fmaxf(ot[r2 * 132 + cs + j], ot[r3 * 132 + cs + j]));
        u32 w[4];
#pragma unroll
        for (int j = 0; j < 4; j++)
            w[j] = (u32)f2h(pv[2 * j]) | ((u32)f2h(pv[2 * j + 1]) << 16);
        *(uint4*)(phH + ((size_t)(b * N2 + mb0 + ml)) * CI + cs) =
            make_uint4(w[0], w[1], w[2], w[3]);
    } else {
        int gci = tid >> 1, half = tid & 1;
        u32 res[4];
#pragma unroll
        for (int p = 0; p < 4; p++) {
            int m0 = half * 8 + 2 * p, m1 = m0 + 1;
            float v0 = fmaxf(fmaxf(ot[(2 * m0) * 132 + gci], ot[(2 * m0 + 1) * 132 + gci]),
                             fmaxf(ot[(32 + 2 * m0) * 132 + gci], ot[(33 + 2 * m0) * 132 + gci]));
            float v1 = fmaxf(fmaxf(ot[(2 * m1) * 132 + gci], ot[(2 * m1 + 1) * 132 + gci]),
                             fmaxf(ot[(32 + 2 * m1) * 132 + gci], ot[(33 + 2 * m1) * 132 + gci]));
            res[p] = (u32)f2h(v0) | ((u32)f2h(v1) << 16);
        }
        *(uint4*)(gH + ((size_t)(b * CI + gci)) * N2 + mb0 + half * 8) =
            make_uint4(res[0], res[1], res[2], res[3]);
    }
    if (nb2 == 0 && mb == 0 && b == 0 && tid == 0) {
        ws32[CAN0_OFF / 4] = CAN0V;
        ws32[CAN1_OFF / 4] = CAN1V;
        ws32[CAN2_OFF / 4] = CAN2V;
    }
}

// ---------------------------------------------------------------------------
// K2 (fused): flash attention + final conv. R6: 8 waves / 512 threads,
// intra-block KV split (group 0: keys [0,1024), group 1: [1024,2048)),
// 2 waves/SIMD for latency hiding. Exact flash-combine merges the groups.
// ---------------------------------------------------------------------------
__global__ __launch_bounds__(512) void attn_fused(
    const u16* __restrict__ thH, const u16* __restrict__ phH,
    const u16* __restrict__ gH, const u16* __restrict__ wfh,
    const float* __restrict__ bfi, const float* __restrict__ gam,
    const float* __restrict__ bet, const float* __restrict__ mea,
    const float* __restrict__ varr, const float* __restrict__ x,
    const u32* __restrict__ ws32, float* __restrict__ out, int b0)
{
    __shared__ __align__(16) u16 kv_s[4][8192];   // [grp*2+buf]: phi 8KB | V 8KB
    __shared__ __align__(16) u16 p_s[8][512];
    __shared__ float cm[64], cl[64];
    __shared__ int flag;

    int tid = threadIdx.x;
    int lane = tid & 63, wid = tid >> 6;
    int l15 = lane & 15, lg = lane >> 4;
    int grp = wid >> 2;          // KV half
    int wq  = wid & 3;           // q sub-tile (16 rows) within group
    int gtid = tid & 255;        // tid within group
    int qb = blockIdx.x, b = b0 + blockIdx.y;

    if (tid == 0) {
        u32 pf = ws32[FLAG_OFF / 4];
        bool ws_ok = ws32[CAN0_OFF / 4] == CAN0V && ws32[CAN1_OFF / 4] == CAN1V &&
                     ws32[CAN2_OFF / 4] == CAN2V;
        bool is_bf16_input = ((pf & 1u) == 0u) && ((pf & 2u) != 0u);
        flag = is_bf16_input ? 2 : (ws_ok ? 0 : 1);
    }

    const u16* phB = phH + (size_t)b * N2 * CI;
    const u16* gB  = gH + (size_t)b * CI * N2;

    uint4 rph0, rph1, rv0, rv1;

#define LOADKV(k0) do {                                                                  \
    rph0 = *(const uint4*)(phB + ((size_t)((k0) + (gtid >> 4))) * CI + (gtid & 15) * 8); \
    rph1 = *(const uint4*)(phB + ((size_t)((k0) + 16 + (gtid >> 4))) * CI + (gtid & 15) * 8); \
    rv0  = *(const uint4*)(gB + (size_t)(gtid >> 2) * N2 + (k0) + (gtid & 3) * 8);       \
    rv1  = *(const uint4*)(gB + (size_t)(64 + (gtid >> 2)) * N2 + (k0) + (gtid & 3) * 8); \
} while (0)

#define WRITEKV(buf) do {                                                                \
    u16* ph_d = kv_s[grp * 2 + (buf)]; u16* v_d = ph_d + 4096;                           \
    { int key = gtid >> 4;        int c8 = gtid & 15;                                    \
      *(uint4*)&ph_d[(key * 128 + c8 * 8) ^ ((key & 7) << 3)] = rph0; }                  \
    { int key = 16 + (gtid >> 4); int c8 = gtid & 15;                                    \
      *(uint4*)&ph_d[(key * 128 + c8 * 8) ^ ((key & 7) << 3)] = rph1; }                  \
    { int d = gtid >> 2;        int m8 = (gtid & 3) * 8;                                 \
      *(uint4*)&v_d[(d * 32 + m8) ^ (((d >> 1) & 3) << 3)] = rv0; }                      \
    { int d = 64 + (gtid >> 2); int m8 = (gtid & 3) * 8;                                 \
      *(uint4*)&v_d[(d * 32 + m8) ^ (((d >> 1) & 3) << 3)] = rv1; }                      \
} while (0)

    // theta A-frags: direct global->reg (waves w and w+4 duplicate, via L2)
    f16x8 ath[4];
    {
        const u16* tp = thH + ((size_t)((b - b0) * NN + qb * 64 + wq * 16 + l15)) * CI;
#pragma unroll
        for (int ks = 0; ks < 4; ks++)
            ath[ks] = *(const f16x8*)(tp + ks * 32 + lg * 8);
    }
    int kbase = grp * 1024;
    LOADKV(kbase);
    WRITEKV(0);
    LOADKV(kbase + 32);
    __syncthreads();

    if (flag) {   // sentinel path (dtype model wrong / ws corrupt)
        float sig = flag == 2 ? 40000.f : 30000.f;
        if (tid < 256) {
            size_t rowb = ((size_t)(b * CC + tid)) * NN + qb * 64;
            for (int n = 0; n < 64; n++) out[rowb + n] = sig;
        }
        return;
    }

    f16x8 ones;
#pragma unroll
    for (int i = 0; i < 8; i++) ones[i] = (f16)1.0f;

    f32x4 Y[8];
#pragma unroll
    for (int i = 0; i < 8; i++) Y[i] = (f32x4){0.f, 0.f, 0.f, 0.f};
    f32x4 Yl = {0.f, 0.f, 0.f, 0.f};
    float m_run[4] = {-1e30f, -1e30f, -1e30f, -1e30f};

    for (int t = 0; t < 32; t++) {
        int cur = t & 1;
        if (t + 1 < 32) WRITEKV(cur ^ 1);
        if (t + 2 < 32) LOADKV(kbase + (t + 2) * 32);

        const u16* ph_c = kv_s[grp * 2 + cur];
        const u16* v_c  = ph_c + 4096;

        f32x4 S0 = {0.f, 0.f, 0.f, 0.f}, S1 = {0.f, 0.f, 0.f, 0.f};
#pragma unroll
        for (int ks = 0; ks < 4; ks++) {
            f16x8 bf0 = *(const f16x8*)&ph_c[(l15 * 128 + ks * 32 + lg * 8) ^ ((l15 & 7) << 3)];
            f16x8 bf1 = *(const f16x8*)&ph_c[((16 + l15) * 128 + ks * 32 + lg * 8) ^ (((16 + l15) & 7) << 3)];
            S0 = __builtin_amdgcn_mfma_f32_16x16x32_f16(ath[ks], bf0, S0, 0, 0, 0);
            S1 = __builtin_amdgcn_mfma_f32_16x16x32_f16(ath[ks], bf1, S1, 0, 0, 0);
        }

        // ---- online softmax, log2 domain ----
        float pmax[4], need = 0.f;
#pragma unroll
        for (int r = 0; r < 4; r++) {
            float v = fmaxf(S0[r], S1[r]);
            v = fmaxf(v, __shfl_xor(v, 1));
            v = fmaxf(v, __shfl_xor(v, 2));
            v = fmaxf(v, __shfl_xor(v, 4));
            v = fmaxf(v, __shfl_xor(v, 8));
            pmax[r] = v;
            need = fmaxf(need, v - m_run[r]);
        }
        if (__any(need > 11.5f)) {   // T13 defer-max
            float al[4];
#pragma unroll
            for (int r = 0; r < 4; r++) {
                float mn = fmaxf(m_run[r], pmax[r]);
                al[r] = __builtin_amdgcn_exp2f(m_run[r] - mn);
                m_run[r] = mn;
            }
#pragma unroll
            for (int i = 0; i < 8; i++) {
#pragma unroll
                for (int r = 0; r < 4; r++) Y[i][r] *= al[r];
            }
#pragma unroll
            for (int r = 0; r < 4; r++) Yl[r] *= al[r];
        }
        float p0[4], p1[4];
#pragma unroll
        for (int r = 0; r < 4; r++) {
            p0[r] = __builtin_amdgcn_exp2f(S0[r] - m_run[r]);
            p1[r] = __builtin_amdgcn_exp2f(S1[r] - m_run[r]);
        }

        {
            u16* pw = p_s[wid];
#pragma unroll
            for (int r = 0; r < 4; r++) {
                int q = lg * 4 + r;
                int sw = ((q >> 1) & 3) << 3;
                pw[(q * 32 + l15) ^ sw]      = f2h(p0[r]);
                pw[(q * 32 + 16 + l15) ^ sw] = f2h(p1[r]);
            }
        }
        __builtin_amdgcn_sched_barrier(0);

        f16x8 pa = *(const f16x8*)&p_s[wid][(l15 * 32 + lg * 8) ^ (((l15 >> 1) & 3) << 3)];
        Yl = __builtin_amdgcn_mfma_f32_16x16x32_f16(pa, ones, Yl, 0, 0, 0);
#pragma unroll
        for (int dt = 0; dt < 8; dt++) {
            int d = dt * 16 + l15;
            f16x8 bv = *(const f16x8*)&v_c[(d * 32 + lg * 8) ^ (((d >> 1) & 3) << 3)];
            Y[dt] = __builtin_amdgcn_mfma_f32_16x16x32_f16(pa, bv, Y[dt], 0, 0, 0);
        }
        __syncthreads();
    }

    // ---- flash-combine: group 1 exports partials (kv area is dead now) ----
    float* cmb = (float*)kv_s[2];   // 32 KB [64 q][128 d] f32, aliases grp-1 kv
    if (grp == 1) {
        if (l15 == 0) {
#pragma unroll
            for (int r = 0; r < 4; r++) {
                int q = wq * 16 + lg * 4 + r;
                cm[q] = m_run[r];
                cl[q] = Yl[r];
            }
        }
#pragma unroll
        for (int dt = 0; dt < 8; dt++) {
#pragma unroll
            for (int r = 0; r < 4; r++) {
                int q = wq * 16 + lg * 4 + r;
                cmb[q * 128 + dt * 16 + l15] = Y[dt][r];
            }
        }
    }
    __syncthreads();

    // ---- group 0 merges (exact), normalizes, writes y -> LDS ----
    u16* yl = (u16*)kv_s[0];   // 16 KB [64 n][128 ci], swz ^((n&7)<<3)
    if (grp == 0) {
        float a0[4], a1[4], linv[4];
#pragma unroll
        for (int r = 0; r < 4; r++) {
            int q = wq * 16 + lg * 4 + r;
            float m1 = cm[q], l1 = cl[q];
            float mm = fmaxf(m_run[r], m1);
            a0[r] = __builtin_amdgcn_exp2f(m_run[r] - mm);
            a1[r] = __builtin_amdgcn_exp2f(m1 - mm);
            linv[r] = 1.f / (Yl[r] * a0[r] + l1 * a1[r]);
        }
#pragma unroll
        for (int dt = 0; dt < 8; dt++) {
#pragma unroll
            for (int r = 0; r < 4; r++) {
                int q = wq * 16 + lg * 4 + r;
                int d = dt * 16 + l15;
                float ym = (Y[dt][r] * a0[r] + cmb[q * 128 + d] * a1[r]) * linv[r];
                yl[(q * 128 + d) ^ ((q & 7) << 3)] = f2h(ym);
            }
        }
    }
    __syncthreads();

    // ---- fused final conv: out[c][n] = wf[c][:]·y[n][:], BN, +x (8 waves) ----
    f16x8 bfr[4][4];
#pragma unroll
    for (int ks = 0; ks < 4; ks++)
#pragma unroll
        for (int ct = 0; ct < 4; ct++) {
            int n = ct * 16 + l15;
            bfr[ks][ct] = *(const f16x8*)&yl[(n * 128 + ks * 32 + lg * 8) ^ ((n & 7) << 3)];
        }

#pragma unroll
    for (int rt = 0; rt < 2; rt++) {
        int cb = wid * 32 + rt * 16;   // 8 waves x 2 = 256 c rows
        f16x8 af[4];
#pragma unroll
        for (int ks = 0; ks < 4; ks++)
            af[ks] = *(const f16x8*)(wfh + (size_t)(cb + l15) * 128 + ks * 32 + lg * 8);
        f32x4 acc2[4];
#pragma unroll
        for (int ct = 0; ct < 4; ct++) acc2[ct] = (f32x4){0.f, 0.f, 0.f, 0.f};
#pragma unroll
        for (int ks = 0; ks < 4; ks++)
#pragma unroll
            for (int ct = 0; ct < 4; ct++)
                acc2[ct] = __builtin_amdgcn_mfma_f32_16x16x32_f16(af[ks], bfr[ks][ct], acc2[ct], 0, 0, 0);

        int c4 = cb + lg * 4;
        float4 g4 = *(const float4*)&gam[c4];
        float4 v4 = *(const float4*)&varr[c4];
        float4 m4 = *(const float4*)&mea[c4];
        float4 t4 = *(const float4*)&bet[c4];
        float4 f4 = *(const float4*)&bfi[c4];
        float iv[4], mn[4], bt[4], bv[4];
        iv[0] = g4.x / sqrtf(v4.x + 1e-5f); iv[1] = g4.y / sqrtf(v4.y + 1e-5f);
        iv[2] = g4.z / sqrtf(v4.z + 1e-5f); iv[3] = g4.w / sqrtf(v4.w + 1e-5f);
        mn[0] = m4.x; mn[1] = m4.y; mn[2] = m4.z; mn[3] = m4.w;
        bt[0] = t4.x; bt[1] = t4.y; bt[2] = t4.z; bt[3] = t4.w;
        bv[0] = f4.x; bv[1] = f4.y; bv[2] = f4.z; bv[3] = f4.w;
#pragma unroll
        for (int ct = 0; ct < 4; ct++) {
            int n = qb * 64 + ct * 16 + l15;
#pragma unroll
            for (int r = 0; r < 4; r++) {
                size_t o = ((size_t)(b * CC + c4 + r)) * NN + n;
                out[o] = (acc2[ct][r] + bv[r] - mn[r]) * iv[r] + bt[r] + x[o];
            }
        }
    }
#undef LOADKV
#undef WRITEKV
}

// ---------------------------------------------------------------------------
extern "C" void kernel_launch(void* const* d_in, const int* in_sizes, int n_in,
                              void* d_out, int out_size, void* d_ws, size_t ws_size,
                              hipStream_t stream)
{
    const int NOUT = BB * CC * NN;   // 8,388,608 elements
    bool sizes_ok = (n_in == 13) && (out_size == NOUT) &&
        in_sizes[0] == NOUT &&
        in_sizes[1] == CI * CC && in_sizes[2] == CI &&
        in_sizes[3] == CI * CC && in_sizes[4] == CI &&
        in_sizes[5] == CI * CC && in_sizes[6] == CI &&
        in_sizes[7] == CC * CI && in_sizes[8] == CC &&
        in_sizes[9] == CC && in_sizes[10] == CC && in_sizes[11] == CC && in_sizes[12] == CC;
    if (!sizes_ok || ws_size < (size_t)WS_NEED) {
        float sig = (!sizes_ok) ? 25000.f : 20000.f;
        hipLaunchKernelGGL(fill_constf, dim3((NOUT + 255) / 256), dim3(256), 0, stream,
                           (float*)d_out, sig, NOUT);
        return;
    }

    const float* x   = (const float*)d_in[0];
    const float* wth = (const float*)d_in[1];
    const float* bth = (const float*)d_in[2];
    const float* wph = (const float*)d_in[3];
    const float* bph = (const float*)d_in[4];
    const float* wg  = (const float*)d_in[5];
    const float* bg  = (const float*)d_in[6];
    const float* wf  = (const float*)d_in[7];
    const float* bfi = (const float*)d_in[8];
    const float* gam = (const float*)d_in[9];
    const float* bet = (const float*)d_in[10];
    const float* mea = (const float*)d_in[11];
    const float* var = (const float*)d_in[12];

    char* ws = (char*)d_ws;
    float* outF = (float*)d_out;                   // 33,554,432 B fp32
    u16*   thA  = (u16*)(outF + 4194304);          // theta b=0,1: d_out [16MB, 20MB)
    u16*   thB  = (u16*)(ws + THB_OFF);            // theta b=2,3: ws, 4 MB
    u16*   phHp = (u16*)(ws + PHI_OFF);
    u16*   gHp  = (u16*)(ws + GP_OFF);
    u16*   wHi  = (u16*)(ws + WHI_OFF);
    u16*   wLo  = (u16*)(ws + WLO_OFF);
    u16*   wFh  = (u16*)(ws + WFH_OFF);
    u32*   part = (u32*)(ws + PART_OFF);
    u32*   w32  = (u32*)ws;

    hipLaunchKernelGGL(probe_x, dim3(2048), dim3(256), 0, stream, (const u32*)x, part);
    hipLaunchKernelGGL(prep_w, dim3(513), dim3(256), 0, stream,
                       wth, wph, wg, wf, wHi, wLo, wFh, part, w32);
    hipLaunchKernelGGL(proj_mfma, dim3(128, 3, 4), dim3(256), 0, stream,
                       x, bth, bph, bg, wHi, wLo, thA, thB, phHp, gHp, w32);
    // Launch 1 (b=0,1): writes out [0,16MB); theta thA at [16,20MB) untouched.
    hipLaunchKernelGGL(attn_fused, dim3(128, 2), dim3(512), 0, stream,
                       thA, phHp, gHp, wFh, bfi, gam, bet, mea, var, x, w32, outF, 0);
    // Launch 2 (b=2,3): writes out [16,32MB) (thA consumed); theta from ws.
    hipLaunchKernelGGL(attn_fused, dim3(128, 2), dim3(512), 0, stream,
                       thB, phHp, gHp, wFh, bfi, gam, bet, mea, var, x, w32, outF, 2);
}

// Round 9
// 207.825 us; speedup vs baseline: 2.2170x; 1.0950x over previous
//
#include <hip/hip_runtime.h>

typedef unsigned short u16;
typedef unsigned int   u32;

#define BB 4
#define CC 256
#define CI 128
#define NN 8192
#define N2 2048

// ws layout (bytes).
#define PHI_OFF   0u           // phi pooled fp16 [b][m][ci]: 4*2048*128*2 = 2,097,152
#define CAN0_OFF  2097152u
#define GP_OFF    2097168u     // g pooled fp16 [b][ci][m]: 2,097,152
#define CAN1_OFF  4194320u
#define THB_OFF   4194336u     // theta fp16 b=2,3: 2*8192*128*2 = 4,194,304
#define CAN2_OFF  8388640u
#define FLAG_OFF  8388644u
#define WHI_OFF   8388672u     // W_hi fp16 [3][128][256]: 196,608
#define WLO_OFF   8585280u     // W_lo fp16 [3][128][256]: 196,608
#define WFH_OFF   8781888u     // wf fp16 [256][128]: 65,536
#define PART_OFF  8847424u     // probe per-block partials: 2048*4 = 8,192
#define WS_NEED   8855616u     // < 10,485,808 proven available

#define CAN0V 0xC0FFEE01u
#define CAN1V 0xC0FFEE02u
#define CAN2V 0xC0FFEE03u

#define LOG2E 1.4426950408889634f

typedef _Float16 f16;
typedef f16 f16x8 __attribute__((ext_vector_type(8)));
typedef float f32x4 __attribute__((ext_vector_type(4)));

__device__ __forceinline__ u16 f2h(float f) {
    _Float16 h = (_Float16)f;
    return __builtin_bit_cast(u16, h);
}
__device__ __forceinline__ float h2f(u16 u) {
    return (float)__builtin_bit_cast(_Float16, u);
}
__device__ __forceinline__ u32 pk2h(float a, float b) {
    return (u32)f2h(a) | ((u32)f2h(b) << 16);
}

// ---------------------------------------------------------------------------
__global__ __launch_bounds__(256) void fill_constf(float* out, float v, int n)
{
    int i = blockIdx.x * 256 + threadIdx.x;
    if (i < n) out[i] = v;
}

// Probe: x viewed as u32 fp32 words. No atomics (R4 lesson): per-block
// plain-store partials; prep_w block 512 combines.
__global__ __launch_bounds__(256) void probe_x(const u32* __restrict__ xv,
                                               u32* __restrict__ part)
{
    __shared__ u32 red[4];
    int tid = threadIdx.x;
    int gid = blockIdx.x * 256 + tid;           // 524,288 threads
    const uint4* p = (const uint4*)xv;          // 2,097,152 uint4 total
    uint4 v0 = p[gid];
    uint4 v1 = p[gid + 524288];
    uint4 v2 = p[gid + 2 * 524288];
    uint4 v3 = p[gid + 3 * 524288];
    u32 ws_[16] = {v0.x, v0.y, v0.z, v0.w, v1.x, v1.y, v1.z, v1.w,
                   v2.x, v2.y, v2.z, v2.w, v3.x, v3.y, v3.z, v3.w};
    bool ff = false, nz = false;
#pragma unroll
    for (int j = 0; j < 16; j++) {
        u32 w = ws_[j];
        u32 lo = w & 0xffffu, hi = w >> 16;
        ff |= ((lo & 0x7f80u) == 0x7f80u) || ((hi & 0x7f80u) == 0x7f80u);
        nz |= (lo != 0u);
    }
    u32 wm = (__any(ff) ? 1u : 0u) | (__any(nz) ? 2u : 0u);
    if ((tid & 63) == 0) red[tid >> 6] = wm;
    __syncthreads();
    if (tid == 0) part[blockIdx.x] = red[0] | red[1] | red[2] | red[3];
}

// ---------------------------------------------------------------------------
// prep_w: blocks 0..511 split proj weights into fp16 hi+lo + wf -> fp16.
// Block 512: OR-combine probe partials -> flag word (runs after probe_x).
// ---------------------------------------------------------------------------
__global__ __launch_bounds__(256) void prep_w(
    const float* __restrict__ w0, const float* __restrict__ w1,
    const float* __restrict__ w2, const float* __restrict__ wf,
    u16* __restrict__ whi, u16* __restrict__ wlo, u16* __restrict__ wfh,
    const u32* __restrict__ part, u32* __restrict__ ws32)
{
    if (blockIdx.x < 512) {
        int idx = blockIdx.x * 256 + threadIdx.x;
        if (idx < 98304) {
            int mb = idx >> 15, r = idx & 32767;
            float w = (mb == 0 ? w0 : (mb == 1 ? w1 : w2))[r];
            u16 hi = f2h(w);
            whi[idx] = hi;
            wlo[idx] = f2h(w - h2f(hi));
        } else {
            int r = idx - 98304;
            wfh[r] = f2h(wf[r]);
        }
    } else {
        __shared__ u32 red[4];
        int tid = threadIdx.x;
        u32 m = 0;
#pragma unroll
        for (int i = 0; i < 8; i++) m |= part[tid * 8 + i];
        m |= __shfl_xor(m, 1);  m |= __shfl_xor(m, 2);  m |= __shfl_xor(m, 4);
        m |= __shfl_xor(m, 8);  m |= __shfl_xor(m, 16); m |= __shfl_xor(m, 32);
        if ((tid & 63) == 0) red[tid >> 6] = m;
        __syncthreads();
        if (tid == 0) ws32[FLAG_OFF / 4] = red[0] | red[1] | red[2] | red[3];
    }
}

// ---------------------------------------------------------------------------
// K1: projections via compensated fp16 MFMA (unchanged from R5 — validated).
// ---------------------------------------------------------------------------
__global__ __launch_bounds__(256) void proj_mfma(
    const float* __restrict__ x,
    const float* __restrict__ b0v, const float* __restrict__ b1v,
    const float* __restrict__ b2v,
    const u16* __restrict__ whi, const u16* __restrict__ wlo,
    u16* __restrict__ thA, u16* __restrict__ thB,
    u16* __restrict__ phH, u16* __restrict__ gH,
    u32* __restrict__ ws32)
{
    __shared__ __align__(16) u16 smem[24576];
    int nb2 = blockIdx.x, mb = blockIdx.y, b = blockIdx.z;
    int tid = threadIdx.x;
    int lane = tid & 63, wid = tid >> 6, l15 = lane & 15, lg = lane >> 4;
    int n0 = nb2 * 64;

    const float* Bv = mb == 0 ? b0v : (mb == 1 ? b1v : b2v);
    const u16* whB = whi + mb * 32768;
    const u16* wlB = wlo + mb * 32768;

    int n_l = tid & 63, cg = tid >> 6;
    const float* xp = x + ((size_t)(b * CC + cg * 8)) * NN + n0 + n_l;
    int wci = tid >> 2, wkc = tid & 3;
    const u16* whp = whB + wci * 256 + wkc * 8;
    const u16* wlp = wlB + wci * 256 + wkc * 8;

    float xr[8];
    uint4 whr0, whr1, wlr0, wlr1;

#define PLOAD(s) do {                                                          \
    _Pragma("unroll") for (int j = 0; j < 8; j++)                              \
        xr[j] = xp[(size_t)((s) * 32 + j) * NN];                               \
    whr0 = *(const uint4*)(whp + (s) * 32);                                    \
    whr1 = *(const uint4*)(whp + 16384 + (s) * 32);                            \
    wlr0 = *(const uint4*)(wlp + (s) * 32);                                    \
    wlr1 = *(const uint4*)(wlp + 16384 + (s) * 32);                            \
} while (0)

#define PWRITE(bf) do {                                                        \
    u16* bp = smem + (bf) * 12288;                                             \
    u32 hw[4], lw[4];                                                          \
    _Pragma("unroll") for (int j = 0; j < 4; j++) {                            \
        u16 h0 = f2h(xr[2 * j]), h1 = f2h(xr[2 * j + 1]);                      \
        u16 q0 = f2h(xr[2 * j] - h2f(h0)), q1 = f2h(xr[2 * j + 1] - h2f(h1));  \
        hw[j] = (u32)h0 | ((u32)h1 << 16);                                     \
        lw[j] = (u32)q0 | ((u32)q1 << 16);                                     \
    }                                                                          \
    int xi = (n_l * 32 + cg * 8) ^ (((n_l >> 1) & 3) << 3);                    \
    *(uint4*)&bp[xi]        = make_uint4(hw[0], hw[1], hw[2], hw[3]);          \
    *(uint4*)&bp[2048 + xi] = make_uint4(lw[0], lw[1], lw[2], lw[3]);          \
    int wi = (wci * 32 + wkc * 8) ^ (((wci >> 1) & 3) << 3);                   \
    *(uint4*)&bp[4096 + wi]        = whr0;                                     \
    *(uint4*)&bp[4096 + wi + 2048] = whr1;                                     \
    *(uint4*)&bp[8192 + wi]        = wlr0;                                     \
    *(uint4*)&bp[8192 + wi + 2048] = wlr1;                                     \
} while (0)

    f32x4 acc[2][4];
#pragma unroll
    for (int i = 0; i < 2; i++)
#pragma unroll
        for (int j = 0; j < 4; j++) acc[i][j] = (f32x4){0.f, 0.f, 0.f, 0.f};

    PLOAD(0);
    PWRITE(0);
    PLOAD(1);
    __syncthreads();

    for (int t = 0; t < 8; t++) {
        int cur = t & 1;
        if (t + 1 < 8) PWRITE(cur ^ 1);
        if (t + 2 < 8) PLOAD(t + 2);
        const u16* bp = smem + cur * 12288;
        f16x8 ah[2], al[2], bh[4], bl[4];
#pragma unroll
        for (int rt = 0; rt < 2; rt++) {
            int r = wid * 32 + rt * 16 + l15;
            int idx = (r * 32 + lg * 8) ^ (((r >> 1) & 3) << 3);
            ah[rt] = *(const f16x8*)&bp[4096 + idx];
            al[rt] = *(const f16x8*)&bp[8192 + idx];
        }
#pragma unroll
        for (int ct = 0; ct < 4; ct++) {
            int n = ct * 16 + l15;
            int idx = (n * 32 + lg * 8) ^ (((n >> 1) & 3) << 3);
            bh[ct] = *(const f16x8*)&bp[idx];
            bl[ct] = *(const f16x8*)&bp[2048 + idx];
        }
#pragma unroll
        for (int rt = 0; rt < 2; rt++)
#pragma unroll
            for (int ct = 0; ct < 4; ct++) {
                acc[rt][ct] = __builtin_amdgcn_mfma_f32_16x16x32_f16(ah[rt], bh[ct], acc[rt][ct], 0, 0, 0);
                acc[rt][ct] = __builtin_amdgcn_mfma_f32_16x16x32_f16(ah[rt], bl[ct], acc[rt][ct], 0, 0, 0);
                acc[rt][ct] = __builtin_amdgcn_mfma_f32_16x16x32_f16(al[rt], bh[ct], acc[rt][ct], 0, 0, 0);
            }
        __syncthreads();
    }
#undef PLOAD
#undef PWRITE

    float* ot = (float*)smem;   // [64][132]
#pragma unroll
    for (int rt = 0; rt < 2; rt++) {
        int cb = wid * 32 + rt * 16 + lg * 4;
        float4 b4 = *(const float4*)&Bv[cb];
#pragma unroll
        for (int ct = 0; ct < 4; ct++) {
            int n = ct * 16 + l15;
            float4 v = make_float4(acc[rt][ct][0] + b4.x, acc[rt][ct][1] + b4.y,
                                   acc[rt][ct][2] + b4.z, acc[rt][ct][3] + b4.w);
            *(float4*)&ot[n * 132 + cb] = v;
        }
    }
    __syncthreads();

    int mb0 = (nb2 >> 4) * 256 + (nb2 & 15) * 16;

    if (mb == 0) {
        int nl = tid >> 2, sg = (tid & 3) * 32;
        u16* base = (b < 2) ? thA : thB;
        u16* dst = base + ((size_t)((b & 1) * NN + n0 + nl)) * CI + sg;
        const float* src = &ot[nl * 132 + sg];
#pragma unroll
        for (int i = 0; i < 4; i++) {
            u32 w[4];
#pragma unroll
            for (int j = 0; j < 4; j++)
                w[j] = (u32)f2h(src[i * 8 + 2 * j] * LOG2E) |
                       ((u32)f2h(src[i * 8 + 2 * j + 1] * LOG2E) << 16);
            ((uint4*)dst)[i] = make_uint4(w[0], w[1], w[2], w[3]);
        }
    } else if (mb == 1) {
        int ml = tid >> 4, cs = (tid & 15) * 8;
        int r0 = 2 * ml, r1 = r0 + 1, r2 = 32 + 2 * ml, r3 = r2 + 1;
        float pv[8];
#pragma unroll
        for (int j = 0; j < 8; j++)
            pv[j] = fmaxf(fmaxf(ot[r0 * 132 + cs + j], ot[r1 * 132 + cs + j]),
                          fmaxf(ot[r2 * 132 + cs + j], ot[r3 * 132 + cs + j]));
        u32 w[4];
#pragma unroll
        for (int j = 0; j < 4; j++)
            w[j] = (u32)f2h(pv[2 * j]) | ((u32)f2h(pv[2 * j + 1]) << 16);
        *(uint4*)(phH + ((size_t)(b * N2 + mb0 + ml)) * CI + cs) =
            make_uint4(w[0], w[1], w[2], w[3]);
    } else {
        int gci = tid >> 1, half = tid & 1;
        u32 res[4];
#pragma unroll
        for (int p = 0; p < 4; p++) {
            int m0 = half * 8 + 2 * p, m1 = m0 + 1;
            float v0 = fmaxf(fmaxf(ot[(2 * m0) * 132 + gci], ot[(2 * m0 + 1) * 132 + gci]),
                             fmaxf(ot[(32 + 2 * m0) * 132 + gci], ot[(33 + 2 * m0) * 132 + gci]));
            float v1 = fmaxf(fmaxf(ot[(2 * m1) * 132 + gci], ot[(2 * m1 + 1) * 132 + gci]),
                             fmaxf(ot[(32 + 2 * m1) * 132 + gci], ot[(33 + 2 * m1) * 132 + gci]));
            res[p] = (u32)f2h(v0) | ((u32)f2h(v1) << 16);
        }
        *(uint4*)(gH + ((size_t)(b * CI + gci)) * N2 + mb0 + half * 8) =
            make_uint4(res[0], res[1], res[2], res[3]);
    }
    if (nb2 == 0 && mb == 0 && b == 0 && tid == 0) {
        ws32[CAN0_OFF / 4] = CAN0V;
        ws32[CAN1_OFF / 4] = CAN1V;
        ws32[CAN2_OFF / 4] = CAN2V;
    }
}

// ---------------------------------------------------------------------------
// K2 (fused): flash attention + final conv. R7: SWAPPED-OPERAND QK^T
// (S^T = mfma(phi, theta)) -> each lane owns one q-row: softmax reductions
// drop from 16 bpermutes to 2 shfl_xor; m/l are per-lane scalars; P^T written
// as 2x b64 and consumed directly as the PV B-fragment (Y^T = mfma(V, P^T)).
// Same math, same precisions. 8 waves, 2 KV groups, flash-combine (exact).
// ---------------------------------------------------------------------------
__global__ __launch_bounds__(512) void attn_fused(
    const u16* __restrict__ thH, const u16* __restrict__ phH,
    const u16* __restrict__ gH, const u16* __restrict__ wfh,
    const float* __restrict__ bfi, const float* __restrict__ gam,
    const float* __restrict__ bet, const float* __restrict__ mea,
    const float* __restrict__ varr, const float* __restrict__ x,
    const u32* __restrict__ ws32, float* __restrict__ out, int b0)
{
    __shared__ __align__(16) u16 kv_s[4][8192];   // [grp*2+buf]: phi 8KB | V 8KB
    __shared__ __align__(16) u16 p_s[8][512];     // per wave: P^T [16 q][32 key]
    __shared__ float cm[64], cl[64];
    __shared__ int flag;

    int tid = threadIdx.x;
    int lane = tid & 63, wid = tid >> 6;
    int l15 = lane & 15, lg = lane >> 4;
    int grp = wid >> 2;          // KV half
    int wq  = wid & 3;           // q sub-tile (16 rows) within group
    int gtid = tid & 255;        // tid within group
    int qb = blockIdx.x, b = b0 + blockIdx.y;

    if (tid == 0) {
        u32 pf = ws32[FLAG_OFF / 4];
        bool ws_ok = ws32[CAN0_OFF / 4] == CAN0V && ws32[CAN1_OFF / 4] == CAN1V &&
                     ws32[CAN2_OFF / 4] == CAN2V;
        bool is_bf16_input = ((pf & 1u) == 0u) && ((pf & 2u) != 0u);
        flag = is_bf16_input ? 2 : (ws_ok ? 0 : 1);
    }

    const u16* phB = phH + (size_t)b * N2 * CI;
    const u16* gB  = gH + (size_t)b * CI * N2;

    uint4 rph0, rph1, rv0, rv1;

#define LOADKV(k0) do {                                                                  \
    rph0 = *(const uint4*)(phB + ((size_t)((k0) + (gtid >> 4))) * CI + (gtid & 15) * 8); \
    rph1 = *(const uint4*)(phB + ((size_t)((k0) + 16 + (gtid >> 4))) * CI + (gtid & 15) * 8); \
    rv0  = *(const uint4*)(gB + (size_t)(gtid >> 2) * N2 + (k0) + (gtid & 3) * 8);       \
    rv1  = *(const uint4*)(gB + (size_t)(64 + (gtid >> 2)) * N2 + (k0) + (gtid & 3) * 8); \
} while (0)

#define WRITEKV(buf) do {                                                                \
    u16* ph_d = kv_s[grp * 2 + (buf)]; u16* v_d = ph_d + 4096;                           \
    { int key = gtid >> 4;        int c8 = gtid & 15;                                    \
      *(uint4*)&ph_d[(key * 128 + c8 * 8) ^ ((key & 7) << 3)] = rph0; }                  \
    { int key = 16 + (gtid >> 4); int c8 = gtid & 15;                                    \
      *(uint4*)&ph_d[(key * 128 + c8 * 8) ^ ((key & 7) << 3)] = rph1; }                  \
    { int d = gtid >> 2;        int m8 = (gtid & 3) * 8;                                 \
      *(uint4*)&v_d[(d * 32 + m8) ^ (((d >> 1) & 3) << 3)] = rv0; }                      \
    { int d = 64 + (gtid >> 2); int m8 = (gtid & 3) * 8;                                 \
      *(uint4*)&v_d[(d * 32 + m8) ^ (((d >> 1) & 3) << 3)] = rv1; }                      \
} while (0)

    // theta fragments: direct global->reg. Used as the B operand of the
    // swapped QK^T (B[k][col=q] = theta[q][k] -- same data as before).
    f16x8 ath[4];
    {
        const u16* tp = thH + ((size_t)((b - b0) * NN + qb * 64 + wq * 16 + l15)) * CI;
#pragma unroll
        for (int ks = 0; ks < 4; ks++)
            ath[ks] = *(const f16x8*)(tp + ks * 32 + lg * 8);
    }
    int kbase = grp * 1024;
    LOADKV(kbase);
    WRITEKV(0);
    LOADKV(kbase + 32);
    __syncthreads();

    if (flag) {   // sentinel path (dtype model wrong / ws corrupt)
        float sig = flag == 2 ? 40000.f : 30000.f;
        if (tid < 256) {
            size_t rowb = ((size_t)(b * CC + tid)) * NN + qb * 64;
            for (int n = 0; n < 64; n++) out[rowb + n] = sig;
        }
        return;
    }

    f16x8 ones;
#pragma unroll
    for (int i = 0; i < 8; i++) ones[i] = (f16)1.0f;

    // Y^T: lane owns q = wq*16 + l15; Y[dt][r] = y[q][d = dt*16 + lg*4 + r]
    f32x4 Y[8];
#pragma unroll
    for (int i = 0; i < 8; i++) Y[i] = (f32x4){0.f, 0.f, 0.f, 0.f};
    f32x4 Yl = {0.f, 0.f, 0.f, 0.f};   // all 4 regs = l[q]
    float m_run = -1e30f;              // per-lane scalar (one q-row)

    int psw = (l15 & 7) << 3;
    u16* pw = p_s[wid];

    for (int t = 0; t < 32; t++) {
        int cur = t & 1;
        if (t + 1 < 32) WRITEKV(cur ^ 1);
        if (t + 2 < 32) LOADKV(kbase + (t + 2) * 32);

        const u16* ph_c = kv_s[grp * 2 + cur];
        const u16* v_c  = ph_c + 4096;

        // ---- QK^T swapped: S^T[key][q], lane owns q=l15, keys {lg*4+r, 16+lg*4+r}
        f32x4 S0 = {0.f, 0.f, 0.f, 0.f}, S1 = {0.f, 0.f, 0.f, 0.f};
#pragma unroll
        for (int ks = 0; ks < 4; ks++) {
            f16x8 bf0 = *(const f16x8*)&ph_c[(l15 * 128 + ks * 32 + lg * 8) ^ ((l15 & 7) << 3)];
            f16x8 bf1 = *(const f16x8*)&ph_c[((16 + l15) * 128 + ks * 32 + lg * 8) ^ (((16 + l15) & 7) << 3)];
            S0 = __builtin_amdgcn_mfma_f32_16x16x32_f16(bf0, ath[ks], S0, 0, 0, 0);
            S1 = __builtin_amdgcn_mfma_f32_16x16x32_f16(bf1, ath[ks], S1, 0, 0, 0);
        }

        // ---- online softmax, log2 domain, scalar per lane ----
        float v = fmaxf(fmaxf(fmaxf(S0[0], S0[1]), fmaxf(S0[2], S0[3])),
                        fmaxf(fmaxf(S1[0], S1[1]), fmaxf(S1[2], S1[3])));
        v = fmaxf(v, __shfl_xor(v, 16));
        v = fmaxf(v, __shfl_xor(v, 32));
        if (__any(v - m_run > 11.5f)) {   // T13 defer-max
            float mn = fmaxf(m_run, v);
            float al = __builtin_amdgcn_exp2f(m_run - mn);
            m_run = mn;
#pragma unroll
            for (int i = 0; i < 8; i++) {
#pragma unroll
                for (int r = 0; r < 4; r++) Y[i][r] *= al;
            }
#pragma unroll
            for (int r = 0; r < 4; r++) Yl[r] *= al;
        }
        float p0[4], p1[4];
#pragma unroll
        for (int r = 0; r < 4; r++) {
            p0[r] = __builtin_amdgcn_exp2f(S0[r] - m_run);
            p1[r] = __builtin_amdgcn_exp2f(S1[r] - m_run);
        }

        // ---- P^T -> LDS [q][key], two packed b64 writes ----
        *(uint2*)&pw[(l15 * 32 + lg * 4) ^ psw] =
            make_uint2(pk2h(p0[0], p0[1]), pk2h(p0[2], p0[3]));
        *(uint2*)&pw[(l15 * 32 + 16 + lg * 4) ^ psw] =
            make_uint2(pk2h(p1[0], p1[1]), pk2h(p1[2], p1[3]));
        __builtin_amdgcn_sched_barrier(0);

        // ---- PV^T: Y^T[d][q] += V[d][k] · P^T[k][q] ----
        f16x8 pb = *(const f16x8*)&pw[(l15 * 32 + lg * 8) ^ psw];
        Yl = __builtin_amdgcn_mfma_f32_16x16x32_f16(ones, pb, Yl, 0, 0, 0);
#pragma unroll
        for (int dt = 0; dt < 8; dt++) {
            int d = dt * 16 + l15;
            f16x8 av = *(const f16x8*)&v_c[(d * 32 + lg * 8) ^ (((d >> 1) & 3) << 3)];
            Y[dt] = __builtin_amdgcn_mfma_f32_16x16x32_f16(av, pb, Y[dt], 0, 0, 0);
        }
        __syncthreads();
    }

    // ---- flash-combine: group 1 exports partials (kv area is dead now) ----
    float* cmb = (float*)kv_s[2];   // 32 KB [64 q][128 d] f32, swz ^((q&7)<<2)
    int q = wq * 16 + l15;
    if (grp == 1) {
        if (lg == 0) {
            cm[q] = m_run;
            cl[q] = Yl[0];
        }
#pragma unroll
        for (int dt = 0; dt < 8; dt++)
            *(f32x4*)&cmb[(q * 128 + dt * 16 + lg * 4) ^ ((q & 7) << 2)] = Y[dt];
    }
    __syncthreads();

    // ---- group 0 merges (exact), normalizes, writes y -> LDS ----
    u16* yl = (u16*)kv_s[0];   // 16 KB [64 n][128 ci], swz ^((n&7)<<3)
    if (grp == 0) {
        float m1 = cm[q], l1 = cl[q];
        float mm = fmaxf(m_run, m1);
        float a0 = __builtin_amdgcn_exp2f(m_run - mm);
        float a1 = __builtin_amdgcn_exp2f(m1 - mm);
        float linv = 1.f / (Yl[0] * a0 + l1 * a1);
#pragma unroll
        for (int dt = 0; dt < 8; dt++) {
            f32x4 c4 = *(const f32x4*)&cmb[(q * 128 + dt * 16 + lg * 4) ^ ((q & 7) << 2)];
            float y0 = (Y[dt][0] * a0 + c4[0] * a1) * linv;
            float y1 = (Y[dt][1] * a0 + c4[1] * a1) * linv;
            float y2 = (Y[dt][2] * a0 + c4[2] * a1) * linv;
            float y3 = (Y[dt][3] * a0 + c4[3] * a1) * linv;
            *(uint2*)&yl[(q * 128 + dt * 16 + lg * 4) ^ ((q & 7) << 3)] =
                make_uint2(pk2h(y0, y1), pk2h(y2, y3));
        }
    }
    __syncthreads();

    // ---- fused final conv: out[c][n] = wf[c][:]·y[n][:], BN, +x (8 waves) ----
    f16x8 bfr[4][4];
#pragma unroll
    for (int ks = 0; ks < 4; ks++)
#pragma unroll
        for (int ct = 0; ct < 4; ct++) {
            int n = ct * 16 + l15;
            bfr[ks][ct] = *(const f16x8*)&yl[(n * 128 + ks * 32 + lg * 8) ^ ((n & 7) << 3)];
        }

#pragma unroll
    for (int rt = 0; rt < 2; rt++) {
        int cb = wid * 32 + rt * 16;   // 8 waves x 2 = 256 c rows
        f16x8 af[4];
#pragma unroll
        for (int ks = 0; ks < 4; ks++)
            af[ks] = *(const f16x8*)(wfh + (size_t)(cb + l15) * 128 + ks * 32 + lg * 8);
        f32x4 acc2[4];
#pragma unroll
        for (int ct = 0; ct < 4; ct++) acc2[ct] = (f32x4){0.f, 0.f, 0.f, 0.f};
#pragma unroll
        for (int ks = 0; ks < 4; ks++)
#pragma unroll
            for (int ct = 0; ct < 4; ct++)
                acc2[ct] = __builtin_amdgcn_mfma_f32_16x16x32_f16(af[ks], bfr[ks][ct], acc2[ct], 0, 0, 0);

        int c4 = cb + lg * 4;
        float4 g4 = *(const float4*)&gam[c4];
        float4 v4 = *(const float4*)&varr[c4];
        float4 m4 = *(const float4*)&mea[c4];
        float4 t4 = *(const float4*)&bet[c4];
        float4 f4 = *(const float4*)&bfi[c4];
        float iv[4], mn[4], bt[4], bv[4];
        iv[0] = g4.x / sqrtf(v4.x + 1e-5f); iv[1] = g4.y / sqrtf(v4.y + 1e-5f);
        iv[2] = g4.z / sqrtf(v4.z + 1e-5f); iv[3] = g4.w / sqrtf(v4.w + 1e-5f);
        mn[0] = m4.x; mn[1] = m4.y; mn[2] = m4.z; mn[3] = m4.w;
        bt[0] = t4.x; bt[1] = t4.y; bt[2] = t4.z; bt[3] = t4.w;
        bv[0] = f4.x; bv[1] = f4.y; bv[2] = f4.z; bv[3] = f4.w;
#pragma unroll
        for (int ct = 0; ct < 4; ct++) {
            int n = qb * 64 + ct * 16 + l15;
#pragma unroll
            for (int r = 0; r < 4; r++) {
                size_t o = ((size_t)(b * CC + c4 + r)) * NN + n;
                out[o] = (acc2[ct][r] + bv[r] - mn[r]) * iv[r] + bt[r] + x[o];
            }
        }
    }
#undef LOADKV
#undef WRITEKV
}

// ---------------------------------------------------------------------------
extern "C" void kernel_launch(void* const* d_in, const int* in_sizes, int n_in,
                              void* d_out, int out_size, void* d_ws, size_t ws_size,
                              hipStream_t stream)
{
    const int NOUT = BB * CC * NN;   // 8,388,608 elements
    bool sizes_ok = (n_in == 13) && (out_size == NOUT) &&
        in_sizes[0] == NOUT &&
        in_sizes[1] == CI * CC && in_sizes[2] == CI &&
        in_sizes[3] == CI * CC && in_sizes[4] == CI &&
        in_sizes[5] == CI * CC && in_sizes[6] == CI &&
        in_sizes[7] == CC * CI && in_sizes[8] == CC &&
        in_sizes[9] == CC && in_sizes[10] == CC && in_sizes[11] == CC && in_sizes[12] == CC;
    if (!sizes_ok || ws_size < (size_t)WS_NEED) {
        float sig = (!sizes_ok) ? 25000.f : 20000.f;
        hipLaunchKernelGGL(fill_constf, dim3((NOUT + 255) / 256), dim3(256), 0, stream,
                           (float*)d_out, sig, NOUT);
        return;
    }

    const float* x   = (const float*)d_in[0];
    const float* wth = (const float*)d_in[1];
    const float* bth = (const float*)d_in[2];
    const float* wph = (const float*)d_in[3];
    const float* bph = (const float*)d_in[4];
    const float* wg  = (const float*)d_in[5];
    const float* bg  = (const float*)d_in[6];
    const float* wf  = (const float*)d_in[7];
    const float* bfi = (const float*)d_in[8];
    const float* gam = (const float*)d_in[9];
    const float* bet = (const float*)d_in[10];
    const float* mea = (const float*)d_in[11];
    const float* var = (const float*)d_in[12];

    char* ws = (char*)d_ws;
    float* outF = (float*)d_out;                   // 33,554,432 B fp32
    u16*   thA  = (u16*)(outF + 4194304);          // theta b=0,1: d_out [16MB, 20MB)
    u16*   thB  = (u16*)(ws + THB_OFF);            // theta b=2,3: ws, 4 MB
    u16*   phHp = (u16*)(ws + PHI_OFF);
    u16*   gHp  = (u16*)(ws + GP_OFF);
    u16*   wHi  = (u16*)(ws + WHI_OFF);
    u16*   wLo  = (u16*)(ws + WLO_OFF);
    u16*   wFh  = (u16*)(ws + WFH_OFF);
    u32*   part = (u32*)(ws + PART_OFF);
    u32*   w32  = (u32*)ws;

    hipLaunchKernelGGL(probe_x, dim3(2048), dim3(256), 0, stream, (const u32*)x, part);
    hipLaunchKernelGGL(prep_w, dim3(513), dim3(256), 0, stream,
                       wth, wph, wg, wf, wHi, wLo, wFh, part, w32);
    hipLaunchKernelGGL(proj_mfma, dim3(128, 3, 4), dim3(256), 0, stream,
                       x, bth, bph, bg, wHi, wLo, thA, thB, phHp, gHp, w32);
    // Launch 1 (b=0,1): writes out [0,16MB); theta thA at [16,20MB) untouched.
    hipLaunchKernelGGL(attn_fused, dim3(128, 2), dim3(512), 0, stream,
                       thA, phHp, gHp, wFh, bfi, gam, bet, mea, var, x, w32, outF, 0);
    // Launch 2 (b=2,3): writes out [16,32MB) (thA consumed); theta from ws.
    hipLaunchKernelGGL(attn_fused, dim3(128, 2), dim3(512), 0, stream,
                       thB, phHp, gHp, wFh, bfi, gam, bet, mea, var, x, w32, outF, 2);
}